// Round 9
// baseline (2145.776 us; speedup 1.0000x reference)
//
#include <hip/hip_runtime.h>
#include <hip/hip_bf16.h>
#include <cstdint>
#include <cstddef>

#define NLAYERS 4
#define SEQ     4096
#define DIMC    1024
#define CHUNKL  128
#define NCHUNK  32
#define HIDF    4096
#define NTOK    8192

using i32x4 = __attribute__((ext_vector_type(4))) int;

__device__ __forceinline__ void gload16(const void* g, void* l) {
    __builtin_amdgcn_global_load_lds((const __attribute__((address_space(1))) void*)g,
                                     (__attribute__((address_space(3))) void*)l, 16, 0, 0);
}

__device__ __forceinline__ float waveSum(float v) {
#pragma unroll
    for (int o = 32; o >= 1; o >>= 1) v += __shfl_down(v, o);
    return v;
}
__device__ __forceinline__ float waveMax(float v) {
#pragma unroll
    for (int o = 32; o >= 1; o >>= 1) v = fmaxf(v, __shfl_down(v, o));
    return v;
}

// ---------------- weight prep: |w| partial sums + sign quant in ONE pass ----------------
__global__ __launch_bounds__(256) void prep_k(const float* __restrict__ w, int8_t* __restrict__ q,
                                              float* __restrict__ part, int perlayer4) {
    __shared__ float red[4];
    int blk = blockIdx.x, layer = blockIdx.y, tid = threadIdx.x;
    const float4* p = (const float4*)(w + (size_t)layer * perlayer4 * 4);
    char4* qp = (char4*)(q + (size_t)layer * perlayer4 * 4);
    float s = 0.f;
    for (int i = blk * 256 + tid; i < perlayer4; i += 256 * 256) {
        float4 v = p[i];
        s += fabsf(v.x) + fabsf(v.y) + fabsf(v.z) + fabsf(v.w);
        char4 o;
        o.x = (v.x > 0.f) ? 1 : ((v.x < 0.f) ? -1 : 0);
        o.y = (v.y > 0.f) ? 1 : ((v.y < 0.f) ? -1 : 0);
        o.z = (v.z > 0.f) ? 1 : ((v.z < 0.f) ? -1 : 0);
        o.w = (v.w > 0.f) ? 1 : ((v.w < 0.f) ? -1 : 0);
        qp[i] = o;
    }
    s = waveSum(s);
    int lane = tid & 63, wv = tid >> 6;
    if (lane == 0) red[wv] = s;
    __syncthreads();
    if (tid == 0) part[layer * 256 + blk] = red[0] + red[1] + red[2] + red[3];
}

__global__ __launch_bounds__(256) void amean_fin(const float* __restrict__ part,
                                                 float* __restrict__ wsc, int perlayer) {
    __shared__ float red[4];
    int layer = blockIdx.x, tid = threadIdx.x;
    float s = part[layer * 256 + tid];
    s = waveSum(s);
    int lane = tid & 63, wv = tid >> 6;
    if (lane == 0) red[wv] = s;
    __syncthreads();
    if (tid == 0) {
        float tot = red[0] + red[1] + red[2] + red[3];
        wsc[layer] = fmaxf(tot / (float)perlayer, 1e-5f);
    }
}

// ---------------- rope tables ----------------
__global__ __launch_bounds__(256) void ropetab_k(float* __restrict__ ct, float* __restrict__ st) {
    int i = blockIdx.x * 256 + threadIdx.x;   // SEQ*32
    int n = i >> 5, j = i & 31;
    float inv = exp2f(-(float)j * (13.287712379549449f / 32.0f)); // 10000^(-j/32)
    float f = (float)n * inv;
    ct[i] = cosf(f);
    st[i] = sinf(f);
}

// rotate a float4 (two rope pairs)
__device__ __forceinline__ float4 rope4(float4 v, const float* ct, const float* st, int n, int j0) {
    float c0 = ct[n * 32 + j0], s0 = st[n * 32 + j0];
    float c1 = ct[n * 32 + j0 + 1], s1 = st[n * 32 + j0 + 1];
    float4 r;
    r.x = v.x * c0 - v.y * s0;
    r.y = v.x * s0 + v.y * c0;
    r.z = v.z * c1 - v.w * s1;
    r.w = v.z * s1 + v.w * c1;
    return r;
}

// ---------------- rmsnorm + row quant (K=1024) ----------------
__global__ __launch_bounds__(256) void rmsq_k(const float* __restrict__ x, const float* __restrict__ w,
                                              int8_t* __restrict__ xq, float* __restrict__ xs) {
    __shared__ float red[4];
    int row = blockIdx.x, tid = threadIdx.x;
    const float4* xr = (const float4*)(x + (size_t)row * DIMC);
    float4 v = xr[tid];
    float ss = v.x * v.x + v.y * v.y + v.z * v.z + v.w * v.w;
    ss = waveSum(ss);
    int lane = tid & 63, wv = tid >> 6;
    if (lane == 0) red[wv] = ss;
    __syncthreads();
    float tot = red[0] + red[1] + red[2] + red[3];
    __syncthreads();
    float rinv = 1.0f / sqrtf(tot * (1.0f / (float)DIMC) + 1e-6f);
    float4 wv4 = ((const float4*)w)[tid];
    float4 y;
    y.x = v.x * rinv * wv4.x; y.y = v.y * rinv * wv4.y;
    y.z = v.z * rinv * wv4.z; y.w = v.w * rinv * wv4.w;
    float mx = fmaxf(fmaxf(fabsf(y.x), fabsf(y.y)), fmaxf(fabsf(y.z), fabsf(y.w)));
    mx = waveMax(mx);
    if (lane == 0) red[wv] = mx;
    __syncthreads();
    float s = fmaxf(fmaxf(fmaxf(red[0], red[1]), fmaxf(red[2], red[3])), 1e-5f);
    if (tid == 0) xs[row] = s;
    float qf = 127.0f / s;
    char4 o;
    o.x = (signed char)(int)rintf(y.x * qf);
    o.y = (signed char)(int)rintf(y.y * qf);
    o.z = (signed char)(int)rintf(y.z * qf);
    o.w = (signed char)(int)rintf(y.w * qf);
    ((char4*)xq)[(size_t)row * 256 + tid] = o;
}

// ---------------- row quant only (K=4096) ----------------
__global__ __launch_bounds__(256) void qrow_k(const float* __restrict__ in,
                                              int8_t* __restrict__ q, float* __restrict__ xs) {
    __shared__ float red[4];
    int row = blockIdx.x, tid = threadIdx.x;
    const float4* xr = (const float4*)(in + (size_t)row * HIDF);
    float4 vv[4];
    float mx = 0.f;
#pragma unroll
    for (int j = 0; j < 4; ++j) {
        vv[j] = xr[j * 256 + tid];
        mx = fmaxf(mx, fmaxf(fmaxf(fabsf(vv[j].x), fabsf(vv[j].y)), fmaxf(fabsf(vv[j].z), fabsf(vv[j].w))));
    }
    mx = waveMax(mx);
    int lane = tid & 63, wv = tid >> 6;
    if (lane == 0) red[wv] = mx;
    __syncthreads();
    float s = fmaxf(fmaxf(fmaxf(red[0], red[1]), fmaxf(red[2], red[3])), 1e-5f);
    if (tid == 0) xs[row] = s;
    float qf = 127.0f / s;
#pragma unroll
    for (int j = 0; j < 4; ++j) {
        char4 o;
        o.x = (signed char)(int)rintf(vv[j].x * qf);
        o.y = (signed char)(int)rintf(vv[j].y * qf);
        o.z = (signed char)(int)rintf(vv[j].z * qf);
        o.w = (signed char)(int)rintf(vv[j].w * qf);
        ((char4*)q)[(size_t)row * 1024 + j * 256 + tid] = o;
    }
}

// ==================== int8 MFMA GEMM, 128x128 tile, BK=64 DOUBLE-BUFFERED prefetch ==========
// T3/T4 minimum 2-phase: STAGE(next buf) issued BEFORE compute(current buf); ONE barrier per
// K-step (its vmcnt(0) drain lands after the MFMAs -> load latency hidden under compute).
// LDS 2x16KB = 32KB/block -> 4 blocks/CU kept. R1-proven BK=64 swizzle geometry.
#define EPI_PLAIN 0
#define EPI_RESID 2

template <int EPI>
__global__ __launch_bounds__(256, 4) void gemm_i8(const int8_t* __restrict__ A,
                                                  const int8_t* __restrict__ B,
                                                  const float* __restrict__ xs,
                                                  const float* __restrict__ wsp,
                                                  const float* __restrict__ bias,
                                                  float* __restrict__ out,
                                                  int N, int K, int ldo) {
    __shared__ __align__(16) int8_t As[2][8192];
    __shared__ __align__(16) int8_t Bs[2][8192];
    const int tid = threadIdx.x;
    const int lane = tid & 63, wave = tid >> 6;
    const int wr = wave >> 1, wc = wave & 1;
    const int bm = blockIdx.x, bn = blockIdx.y;

    const int r0 = tid >> 2, sl = tid & 3;
    const int c0 = ((sl ^ ((r0 >> 1) & 3)) << 4);   // pre-swizzled source column
    const int r1 = r0 + 64;                          // (r1>>1)&3 == (r0>>1)&3
    const int8_t* a0 = A + (size_t)(bm * 128 + r0) * K + c0;
    const int8_t* a1 = A + (size_t)(bm * 128 + r1) * K + c0;
    const int8_t* b0 = B + (size_t)(bn * 128 + r0) * K + c0;
    const int8_t* b1 = B + (size_t)(bn * 128 + r1) * K + c0;

    i32x4 acc[4][4] = {};
    const int fr = lane & 15, ks = lane >> 4;

    // prologue: stage tile 0 into buffer 0
    gload16(a0, As[0] + tid * 16);
    gload16(a1, As[0] + 4096 + tid * 16);
    gload16(b0, Bs[0] + tid * 16);
    gload16(b1, Bs[0] + 4096 + tid * 16);
    __syncthreads();

    int cur = 0;
    for (int kt = 0; kt < K; kt += 64) {
        if (kt + 64 < K) {   // prefetch next tile into the other buffer
            gload16(a0 + kt + 64, As[cur ^ 1] + tid * 16);
            gload16(a1 + kt + 64, As[cur ^ 1] + 4096 + tid * 16);
            gload16(b0 + kt + 64, Bs[cur ^ 1] + tid * 16);
            gload16(b1 + kt + 64, Bs[cur ^ 1] + 4096 + tid * 16);
        }
        i32x4 af[4], bf[4];
#pragma unroll
        for (int m = 0; m < 4; ++m) {
            int ra = wr * 64 + m * 16 + fr;
            af[m] = *(const i32x4*)(As[cur] + ra * 64 + ((ks ^ ((ra >> 1) & 3)) << 4));
        }
#pragma unroll
        for (int n = 0; n < 4; ++n) {
            int rb = wc * 64 + n * 16 + fr;
            bf[n] = *(const i32x4*)(Bs[cur] + rb * 64 + ((ks ^ ((rb >> 1) & 3)) << 4));
        }
#pragma unroll
        for (int m = 0; m < 4; ++m)
#pragma unroll
            for (int n = 0; n < 4; ++n)
                acc[m][n] = __builtin_amdgcn_mfma_i32_16x16x64_i8(af[m], bf[n], acc[m][n], 0, 0, 0);
        __syncthreads();   // drains prefetch (vmcnt) + guards buffer reuse
        cur ^= 1;
    }

    const float ws = *wsp;
#pragma unroll
    for (int m = 0; m < 4; ++m) {
        int row0 = bm * 128 + wr * 64 + m * 16 + ks * 4;
#pragma unroll
        for (int n = 0; n < 4; ++n) {
            int col = bn * 128 + wc * 64 + n * 16 + fr;
            float bv = bias[col];
#pragma unroll
            for (int j = 0; j < 4; ++j) {
                int row = row0 + j;
                float v = (float)acc[m][n][j] * (xs[row] * ws * (1.0f / 127.0f)) + bv;
                size_t idx = (size_t)row * ldo + col;
                if (EPI == EPI_PLAIN) out[idx] = v;
                else                  out[idx] += v;   // EPI_RESID
            }
        }
    }
    (void)N;
}

// ---------------- gate GEMM + sigmoid + chunk-mean fused (dbuf core) ----------------
__global__ __launch_bounds__(256, 4) void gate_decay(const int8_t* __restrict__ A,
                                                     const int8_t* __restrict__ B,
                                                     const float* __restrict__ xs,
                                                     const float* __restrict__ wsp,
                                                     const float* __restrict__ bias,
                                                     float* __restrict__ dec) {
    __shared__ __align__(16) int8_t As[2][8192];
    __shared__ __align__(16) int8_t Bs[2][8192];
    __shared__ float dsum[2][128];
    const int tid = threadIdx.x;
    const int lane = tid & 63, wave = tid >> 6;
    const int wr = wave >> 1, wc = wave & 1;
    const int bm = blockIdx.x, bn = blockIdx.y;
    const int K = 1024;

    const int r0 = tid >> 2, sl = tid & 3;
    const int c0 = ((sl ^ ((r0 >> 1) & 3)) << 4);
    const int r1 = r0 + 64;
    const int8_t* a0 = A + (size_t)(bm * 128 + r0) * K + c0;
    const int8_t* a1 = A + (size_t)(bm * 128 + r1) * K + c0;
    const int8_t* b0 = B + (size_t)(bn * 128 + r0) * K + c0;
    const int8_t* b1 = B + (size_t)(bn * 128 + r1) * K + c0;

    i32x4 acc[4][4] = {};
    const int fr = lane & 15, ks = lane >> 4;

    gload16(a0, As[0] + tid * 16);
    gload16(a1, As[0] + 4096 + tid * 16);
    gload16(b0, Bs[0] + tid * 16);
    gload16(b1, Bs[0] + 4096 + tid * 16);
    __syncthreads();

    int cur = 0;
    for (int kt = 0; kt < K; kt += 64) {
        if (kt + 64 < K) {
            gload16(a0 + kt + 64, As[cur ^ 1] + tid * 16);
            gload16(a1 + kt + 64, As[cur ^ 1] + 4096 + tid * 16);
            gload16(b0 + kt + 64, Bs[cur ^ 1] + tid * 16);
            gload16(b1 + kt + 64, Bs[cur ^ 1] + 4096 + tid * 16);
        }
        i32x4 af[4], bf[4];
#pragma unroll
        for (int m = 0; m < 4; ++m) {
            int ra = wr * 64 + m * 16 + fr;
            af[m] = *(const i32x4*)(As[cur] + ra * 64 + ((ks ^ ((ra >> 1) & 3)) << 4));
        }
#pragma unroll
        for (int n = 0; n < 4; ++n) {
            int rb = wc * 64 + n * 16 + fr;
            bf[n] = *(const i32x4*)(Bs[cur] + rb * 64 + ((ks ^ ((rb >> 1) & 3)) << 4));
        }
#pragma unroll
        for (int m = 0; m < 4; ++m)
#pragma unroll
            for (int n = 0; n < 4; ++n)
                acc[m][n] = __builtin_amdgcn_mfma_i32_16x16x64_i8(af[m], bf[n], acc[m][n], 0, 0, 0);
        __syncthreads();
        cur ^= 1;
    }

    const float ws = *wsp;
#pragma unroll
    for (int n = 0; n < 4; ++n) {
        int col = bn * 128 + wc * 64 + n * 16 + fr;
        float bv = bias[col];
        float sn = 0.f;
#pragma unroll
        for (int m = 0; m < 4; ++m) {
            int row0 = bm * 128 + wr * 64 + m * 16 + ks * 4;
#pragma unroll
            for (int j = 0; j < 4; ++j) {
                int row = row0 + j;
                float v = (float)acc[m][n][j] * (xs[row] * ws * (1.0f / 127.0f)) + bv;
                sn += 1.0f / (1.0f + expf(-v));
            }
        }
        sn += __shfl_down(sn, 32);
        sn += __shfl_down(sn, 16);
        if (lane < 16) dsum[wr][wc * 64 + n * 16 + lane] = sn;
    }
    __syncthreads();
    if (tid < 128) {
        int b = bm >> 5, c = bm & 31;
        dec[(size_t)(c * 2 + b) * 1024 + bn * 128 + tid] =
            (dsum[0][tid] + dsum[1][tid]) * (1.0f / 128.0f);
    }
}

// ---------------- fc1 fused dual-B GEMM + SwiGLU, 128x64 tile, dbuf BK=64 ----------------
__global__ __launch_bounds__(256, 4) void gemm_fc1(const int8_t* __restrict__ A,
                                                   const int8_t* __restrict__ B1,
                                                   const int8_t* __restrict__ B2,
                                                   const float* __restrict__ xs,
                                                   const float* __restrict__ wsp,
                                                   const float* __restrict__ bias,
                                                   float* __restrict__ out) {
    __shared__ __align__(16) int8_t As[2][8192];
    __shared__ __align__(16) int8_t Bs1[2][4096];
    __shared__ __align__(16) int8_t Bs2[2][4096];
    const int tid = threadIdx.x;
    const int lane = tid & 63, wave = tid >> 6;
    const int wr = wave >> 1, wc = wave & 1;   // 2x2 waves over (128 rows, 64 cols)
    const int bm = blockIdx.x, bn = blockIdx.y;
    const int K = 1024;

    const int r0 = tid >> 2, sl = tid & 3;           // r0 in [0,64)
    const int c0 = ((sl ^ ((r0 >> 1) & 3)) << 4);
    const int r1 = r0 + 64;
    const int8_t* a0  = A  + (size_t)(bm * 128 + r0) * K + c0;
    const int8_t* a1  = A  + (size_t)(bm * 128 + r1) * K + c0;
    const int8_t* b1p = B1 + (size_t)(bn * 64 + r0) * K + c0;   // 64-row B tiles
    const int8_t* b2p = B2 + (size_t)(bn * 64 + r0) * K + c0;

    i32x4 acc1[4][2] = {}, acc2[4][2] = {};
    const int fr = lane & 15, ks = lane >> 4;

    gload16(a0,  As[0] + tid * 16);
    gload16(a1,  As[0] + 4096 + tid * 16);
    gload16(b1p, Bs1[0] + tid * 16);
    gload16(b2p, Bs2[0] + tid * 16);
    __syncthreads();

    int cur = 0;
    for (int kt = 0; kt < K; kt += 64) {
        if (kt + 64 < K) {
            gload16(a0  + kt + 64, As[cur ^ 1] + tid * 16);
            gload16(a1  + kt + 64, As[cur ^ 1] + 4096 + tid * 16);
            gload16(b1p + kt + 64, Bs1[cur ^ 1] + tid * 16);
            gload16(b2p + kt + 64, Bs2[cur ^ 1] + tid * 16);
        }
        i32x4 af[4], b1f[2], b2f[2];
#pragma unroll
        for (int m = 0; m < 4; ++m) {
            int ra = wr * 64 + m * 16 + fr;
            af[m] = *(const i32x4*)(As[cur] + ra * 64 + ((ks ^ ((ra >> 1) & 3)) << 4));
        }
#pragma unroll
        for (int n = 0; n < 2; ++n) {
            int rb = wc * 32 + n * 16 + fr;          // [0,64)
            int off = rb * 64 + ((ks ^ ((rb >> 1) & 3)) << 4);
            b1f[n] = *(const i32x4*)(Bs1[cur] + off);
            b2f[n] = *(const i32x4*)(Bs2[cur] + off);
        }
#pragma unroll
        for (int m = 0; m < 4; ++m)
#pragma unroll
            for (int n = 0; n < 2; ++n) {
                acc1[m][n] = __builtin_amdgcn_mfma_i32_16x16x64_i8(af[m], b1f[n], acc1[m][n], 0, 0, 0);
                acc2[m][n] = __builtin_amdgcn_mfma_i32_16x16x64_i8(af[m], b2f[n], acc2[m][n], 0, 0, 0);
            }
        __syncthreads();
        cur ^= 1;
    }

    const float ws = *wsp;
#pragma unroll
    for (int m = 0; m < 4; ++m) {
        int row0 = bm * 128 + wr * 64 + m * 16 + ks * 4;
#pragma unroll
        for (int n = 0; n < 2; ++n) {
            int col = bn * 64 + wc * 32 + n * 16 + fr;
            float ba = bias[col];
            float bg = bias[col + 4096];
#pragma unroll
            for (int j = 0; j < 4; ++j) {
                int row = row0 + j;
                float sc = xs[row] * ws * (1.0f / 127.0f);
                float a = (float)acc1[m][n][j] * sc + ba;
                float g = (float)acc2[m][n][j] * sc + bg;
                out[(size_t)row * HIDF + col] = a * g / (1.0f + expf(-g));
            }
        }
    }
}

// ---------------- per-token head-mix softmax attention (rope fused on q,k) ----------------
__global__ __launch_bounds__(256) void attn_intra(const float* __restrict__ qkv,
                                                  const float* __restrict__ ct,
                                                  const float* __restrict__ st,
                                                  float* __restrict__ o) {
    __shared__ float q_s[1024], k_s[1024], v_s[1024], p_s[256];
    int t = blockIdx.x, tid = threadIdx.x;
    int n = t & (SEQ - 1);
    int j0 = (tid & 15) * 2;
    const float4* src = (const float4*)(qkv + (size_t)t * 3072);
    ((float4*)q_s)[tid] = rope4(src[tid], ct, st, n, j0);
    ((float4*)k_s)[tid] = rope4(src[256 + tid], ct, st, n, j0);
    ((float4*)v_s)[tid] = src[512 + tid];
    __syncthreads();
    int h = tid >> 4, g = tid & 15;
    const float4* q4 = (const float4*)q_s + h * 16;
    const float4* k4 = (const float4*)k_s + g * 16;
    float accS = 0.f;
#pragma unroll
    for (int i = 0; i < 16; ++i) {
        float4 qa = q4[i], ka = k4[i];
        accS += qa.x * ka.x + qa.y * ka.y + qa.z * ka.z + qa.w * ka.w;
    }
    accS *= 0.125f;
    float mx = accS;
#pragma unroll
    for (int o2 = 8; o2 >= 1; o2 >>= 1) mx = fmaxf(mx, __shfl_xor(mx, o2, 16));
    float e = expf(accS - mx);
    float sm = e;
#pragma unroll
    for (int o2 = 8; o2 >= 1; o2 >>= 1) sm += __shfl_xor(sm, o2, 16);
    p_s[tid] = e / sm;
    __syncthreads();
    int dq = tid & 15;
    float4 acc = {0.f, 0.f, 0.f, 0.f};
    const float4* v4 = (const float4*)v_s;
#pragma unroll
    for (int gg = 0; gg < 16; ++gg) {
        float p = p_s[h * 16 + gg];
        float4 vv = v4[gg * 16 + dq];
        acc.x += p * vv.x; acc.y += p * vv.y; acc.z += p * vv.z; acc.w += p * vv.w;
    }
    ((float4*)(o + (size_t)t * DIMC))[h * 16 + dq] = acc;
}

// ---------------- per-chunk outer product U = k^T v (rope fused on k) ----------------
__global__ __launch_bounds__(256) void u_k(const float* __restrict__ qkv,
                                           const float* __restrict__ ct,
                                           const float* __restrict__ st,
                                           float* __restrict__ U) {
    __shared__ float ks_[8192], vs_[8192];
    int bid = blockIdx.x, tid = threadIdx.x;
    int c = bid >> 5, b = (bid >> 4) & 1, h = bid & 15;
    size_t tok = (size_t)(b * SEQ + c * CHUNKL);
#pragma unroll
    for (int j = 0; j < 8; ++j) {
        int idx = j * 256 + tid;
        int l = idx >> 4, c4 = idx & 15;
        int n = (int)((tok + l) & (SEQ - 1));
        const float* kp = qkv + (tok + l) * 3072 + 1024 + h * 64 + c4 * 4;
        const float* vp = qkv + (tok + l) * 3072 + 2048 + h * 64 + c4 * 4;
        ((float4*)ks_)[idx] = rope4(*(const float4*)kp, ct, st, n, c4 * 2);
        ((float4*)vs_)[idx] = *(const float4*)vp;
    }
    __syncthreads();
    int d = tid >> 2, eg = tid & 3;
    float4 acc[4] = {};
    for (int l = 0; l < CHUNKL; ++l) {
        float kd = ks_[l * 64 + d];
        const float4* vrow = (const float4*)(vs_ + l * 64) + eg * 4;
#pragma unroll
        for (int i = 0; i < 4; ++i) {
            float4 vv = vrow[i];
            acc[i].x += kd * vv.x; acc[i].y += kd * vv.y;
            acc[i].z += kd * vv.z; acc[i].w += kd * vv.w;
        }
    }
    float4* Up = (float4*)(U + (size_t)bid * 4096) + d * 16 + eg * 4;
#pragma unroll
    for (int i = 0; i < 4; ++i) Up[i] = acc[i];
}

// ---------------- diagonal-decay scan over chunks ----------------
__global__ __launch_bounds__(256) void scan_k(const float* __restrict__ U,
                                              const float* __restrict__ dec,
                                              float* __restrict__ kvprev) {
    int t = blockIdx.x * 256 + threadIdx.x;   // 131072
    int b = t >> 16;
    int h = (t >> 12) & 15;
    int d = (t >> 6) & 63;
    float val = 0.f;
#pragma unroll 1
    for (int c = 0; c < NCHUNK; ++c) {
        kvprev[(size_t)c * 131072 + t] = val;
        val = val * dec[(c * 2 + b) * 1024 + h * 64 + d] + U[(size_t)c * 131072 + t];
    }
}

// ---------------- out += q @ kv_prev (rope fused on q) ----------------
__global__ __launch_bounds__(256) void out2_k(const float* __restrict__ qkv,
                                              const float* __restrict__ ct,
                                              const float* __restrict__ st,
                                              const float* __restrict__ kvprev,
                                              float* __restrict__ o) {
    __shared__ float kv_s[4096];
    __shared__ float q_s[128 * 65];
    int bid = blockIdx.x, tid = threadIdx.x;
    int c = bid >> 5, b = (bid >> 4) & 1, h = bid & 15;
    size_t tok = (size_t)(b * SEQ + c * CHUNKL);
    const float4* kvsrc = (const float4*)(kvprev + (size_t)c * 131072 + b * 65536 + h * 4096);
#pragma unroll
    for (int j = 0; j < 4; ++j) ((float4*)kv_s)[j * 256 + tid] = kvsrc[j * 256 + tid];
#pragma unroll
    for (int j = 0; j < 8; ++j) {
        int idx = j * 256 + tid;
        int l = idx >> 4, c4 = idx & 15;
        int n = (int)((tok + l) & (SEQ - 1));
        float4 qv = rope4(*(const float4*)(qkv + (tok + l) * 3072 + h * 64 + c4 * 4),
                          ct, st, n, c4 * 2);
        float* dq = q_s + l * 65 + c4 * 4;
        dq[0] = qv.x; dq[1] = qv.y; dq[2] = qv.z; dq[3] = qv.w;
    }
    __syncthreads();
    int l = tid >> 1, eh = tid & 1;
    float4 acc[8] = {};
    const float* qrow = q_s + l * 65;
    for (int d = 0; d < 64; ++d) {
        float qd = qrow[d];
        const float4* kvr = (const float4*)(kv_s + d * 64) + eh * 8;
#pragma unroll
        for (int i = 0; i < 8; ++i) {
            float4 kk = kvr[i];
            acc[i].x += qd * kk.x; acc[i].y += qd * kk.y;
            acc[i].z += qd * kk.z; acc[i].w += qd * kk.w;
        }
    }
    float4* op = (float4*)(o + (tok + l) * DIMC + h * 64 + eh * 32);
#pragma unroll
    for (int i = 0; i < 8; ++i) {
        float4 cur = op[i];
        cur.x += acc[i].x; cur.y += acc[i].y; cur.z += acc[i].z; cur.w += acc[i].w;
        op[i] = cur;
    }
}

// =====================================================================
extern "C" void kernel_launch(void* const* d_in, const int* in_sizes, int n_in,
                              void* d_out, int out_size, void* d_ws, size_t ws_size,
                              hipStream_t stream) {
    const float* x_in       = (const float*)d_in[0];
    const float* norm1_w    = (const float*)d_in[1];
    const float* qkv_w      = (const float*)d_in[2];
    const float* qkv_b      = (const float*)d_in[3];
    const float* gate_w     = (const float*)d_in[4];
    const float* gate_b     = (const float*)d_in[5];
    const float* proj_w     = (const float*)d_in[6];
    const float* proj_b     = (const float*)d_in[7];
    const float* attn_norm_w= (const float*)d_in[8];
    const float* norm2_w    = (const float*)d_in[9];
    const float* fc1_w      = (const float*)d_in[10];
    const float* fc1_b      = (const float*)d_in[11];
    const float* fc2_w      = (const float*)d_in[12];
    const float* fc2_b      = (const float*)d_in[13];
    float* x = (float*)d_out;

    char* wsb = (char*)d_ws;
    size_t off = 0;
    auto carve = [&](size_t bytes) { char* p = wsb + off; off = (off + bytes + 255) & ~(size_t)255; return p; };
    int8_t* q_qkv  = (int8_t*)carve(12582912);
    int8_t* q_gate = (int8_t*)carve(4194304);
    int8_t* q_proj = (int8_t*)carve(4194304);
    int8_t* q_fc1  = (int8_t*)carve(33554432);
    int8_t* q_fc2  = (int8_t*)carve(16777216);
    float*  wsc    = (float*)carve(256);
    float*  part   = (float*)carve(4096);
    float*  ropec  = (float*)carve(524288);
    float*  ropes  = (float*)carve(524288);
    int8_t* qbuf   = (int8_t*)carve(33554432);
    float*  xsbuf  = (float*)carve(32768);
    float*  big    = (float*)carve(134217728);   // qkv(100MB) / fc1-mid(134MB)
    float*  attn_o = (float*)carve(33554432);
    float*  Ub     = (float*)carve(16777216);
    float*  kvprev = (float*)carve(16777216);
    float*  decayb = (float*)carve(262144);
    (void)ws_size; (void)in_sizes; (void)n_in; (void)out_size;

    hipMemcpyAsync(x, x_in, (size_t)NTOK * DIMC * sizeof(float), hipMemcpyDeviceToDevice, stream);
    ropetab_k<<<512, 256, 0, stream>>>(ropec, ropes);

    struct WSpec { const float* w; int8_t* q; int perlayer; int arr; };
    WSpec specs[5] = {
        {qkv_w,  q_qkv,  3 * DIMC * DIMC, 0},
        {gate_w, q_gate, DIMC * DIMC,     1},
        {proj_w, q_proj, DIMC * DIMC,     2},
        {fc1_w,  q_fc1,  8192 * 1024,     3},
        {fc2_w,  q_fc2,  DIMC * HIDF,     4},
    };
    for (int a = 0; a < 5; ++a) {
        prep_k<<<dim3(256, NLAYERS), 256, 0, stream>>>(specs[a].w, specs[a].q, part, specs[a].perlayer / 4);
        amean_fin<<<NLAYERS, 256, 0, stream>>>(part, wsc + specs[a].arr * 4, specs[a].perlayer);
    }

    for (int l = 0; l < NLAYERS; ++l) {
        // ---- attention ----
        rmsq_k<<<NTOK, 256, 0, stream>>>(x, norm1_w + l * DIMC, qbuf, xsbuf);
        gemm_i8<EPI_PLAIN><<<dim3(64, 24), 256, 0, stream>>>(
            qbuf, q_qkv + (size_t)l * 3145728, xsbuf, wsc + 0 * 4 + l,
            qkv_b + l * 3072, big, 3072, 1024, 3072);
        gate_decay<<<dim3(64, 8), 256, 0, stream>>>(
            qbuf, q_gate + (size_t)l * 1048576, xsbuf, wsc + 1 * 4 + l,
            gate_b + l * DIMC, decayb);
        attn_intra<<<NTOK, 256, 0, stream>>>(big, ropec, ropes, attn_o);
        u_k<<<1024, 256, 0, stream>>>(big, ropec, ropes, Ub);
        scan_k<<<512, 256, 0, stream>>>(Ub, decayb, kvprev);
        out2_k<<<1024, 256, 0, stream>>>(big, ropec, ropes, kvprev, attn_o);
        rmsq_k<<<NTOK, 256, 0, stream>>>(attn_o, attn_norm_w + l * DIMC, qbuf, xsbuf);
        gemm_i8<EPI_RESID><<<dim3(64, 8), 256, 0, stream>>>(
            qbuf, q_proj + (size_t)l * 1048576, xsbuf, wsc + 2 * 4 + l,
            proj_b + l * DIMC, x, 1024, 1024, 1024);
        // ---- mlp ----
        rmsq_k<<<NTOK, 256, 0, stream>>>(x, norm2_w + l * DIMC, qbuf, xsbuf);
        gemm_fc1<<<dim3(64, 64), 256, 0, stream>>>(
            qbuf, q_fc1 + (size_t)l * 8388608, q_fc1 + (size_t)l * 8388608 + 4194304,
            xsbuf, wsc + 3 * 4 + l, fc1_b + l * 8192, big);
        qrow_k<<<NTOK, 256, 0, stream>>>(big, qbuf, xsbuf);
        gemm_i8<EPI_RESID><<<dim3(64, 8), 256, 0, stream>>>(
            qbuf, q_fc2 + (size_t)l * 4194304, xsbuf, wsc + 4 * 4 + l,
            fc2_b + l * DIMC, x, 1024, 4096, 1024);
    }
}

// Round 10
// 2024.476 us; speedup vs baseline: 1.0599x; 1.0599x over previous
//
#include <hip/hip_runtime.h>
#include <hip/hip_bf16.h>
#include <cstdint>
#include <cstddef>

#define NLAYERS 4
#define SEQ     4096
#define DIMC    1024
#define CHUNKL  128
#define NCHUNK  32
#define HIDF    4096
#define NTOK    8192

using i32x4 = __attribute__((ext_vector_type(4))) int;

__device__ __forceinline__ void gload16(const void* g, void* l) {
    __builtin_amdgcn_global_load_lds((const __attribute__((address_space(1))) void*)g,
                                     (__attribute__((address_space(3))) void*)l, 16, 0, 0);
}

__device__ __forceinline__ float waveSum(float v) {
#pragma unroll
    for (int o = 32; o >= 1; o >>= 1) v += __shfl_down(v, o);
    return v;
}
__device__ __forceinline__ float waveMax(float v) {
#pragma unroll
    for (int o = 32; o >= 1; o >>= 1) v = fmaxf(v, __shfl_down(v, o));
    return v;
}

// ---------------- weight prep: |w| partial sums + sign quant in ONE pass ----------------
__global__ __launch_bounds__(256) void prep_k(const float* __restrict__ w, int8_t* __restrict__ q,
                                              float* __restrict__ part, int perlayer4) {
    __shared__ float red[4];
    int blk = blockIdx.x, layer = blockIdx.y, tid = threadIdx.x;
    const float4* p = (const float4*)(w + (size_t)layer * perlayer4 * 4);
    char4* qp = (char4*)(q + (size_t)layer * perlayer4 * 4);
    float s = 0.f;
    for (int i = blk * 256 + tid; i < perlayer4; i += 256 * 256) {
        float4 v = p[i];
        s += fabsf(v.x) + fabsf(v.y) + fabsf(v.z) + fabsf(v.w);
        char4 o;
        o.x = (v.x > 0.f) ? 1 : ((v.x < 0.f) ? -1 : 0);
        o.y = (v.y > 0.f) ? 1 : ((v.y < 0.f) ? -1 : 0);
        o.z = (v.z > 0.f) ? 1 : ((v.z < 0.f) ? -1 : 0);
        o.w = (v.w > 0.f) ? 1 : ((v.w < 0.f) ? -1 : 0);
        qp[i] = o;
    }
    s = waveSum(s);
    int lane = tid & 63, wv = tid >> 6;
    if (lane == 0) red[wv] = s;
    __syncthreads();
    if (tid == 0) part[layer * 256 + blk] = red[0] + red[1] + red[2] + red[3];
}

__global__ __launch_bounds__(256) void amean_fin(const float* __restrict__ part,
                                                 float* __restrict__ wsc, int perlayer) {
    __shared__ float red[4];
    int layer = blockIdx.x, tid = threadIdx.x;
    float s = part[layer * 256 + tid];
    s = waveSum(s);
    int lane = tid & 63, wv = tid >> 6;
    if (lane == 0) red[wv] = s;
    __syncthreads();
    if (tid == 0) {
        float tot = red[0] + red[1] + red[2] + red[3];
        wsc[layer] = fmaxf(tot / (float)perlayer, 1e-5f);
    }
}

// ---------------- rope tables ----------------
__global__ __launch_bounds__(256) void ropetab_k(float* __restrict__ ct, float* __restrict__ st) {
    int i = blockIdx.x * 256 + threadIdx.x;   // SEQ*32
    int n = i >> 5, j = i & 31;
    float inv = exp2f(-(float)j * (13.287712379549449f / 32.0f)); // 10000^(-j/32)
    float f = (float)n * inv;
    ct[i] = cosf(f);
    st[i] = sinf(f);
}

// rotate a float4 (two rope pairs)
__device__ __forceinline__ float4 rope4(float4 v, const float* ct, const float* st, int n, int j0) {
    float c0 = ct[n * 32 + j0], s0 = st[n * 32 + j0];
    float c1 = ct[n * 32 + j0 + 1], s1 = st[n * 32 + j0 + 1];
    float4 r;
    r.x = v.x * c0 - v.y * s0;
    r.y = v.x * s0 + v.y * c0;
    r.z = v.z * c1 - v.w * s1;
    r.w = v.z * s1 + v.w * c1;
    return r;
}

// ---------------- rmsnorm + row quant (K=1024) ----------------
__global__ __launch_bounds__(256) void rmsq_k(const float* __restrict__ x, const float* __restrict__ w,
                                              int8_t* __restrict__ xq, float* __restrict__ xs) {
    __shared__ float red[4];
    int row = blockIdx.x, tid = threadIdx.x;
    const float4* xr = (const float4*)(x + (size_t)row * DIMC);
    float4 v = xr[tid];
    float ss = v.x * v.x + v.y * v.y + v.z * v.z + v.w * v.w;
    ss = waveSum(ss);
    int lane = tid & 63, wv = tid >> 6;
    if (lane == 0) red[wv] = ss;
    __syncthreads();
    float tot = red[0] + red[1] + red[2] + red[3];
    __syncthreads();
    float rinv = 1.0f / sqrtf(tot * (1.0f / (float)DIMC) + 1e-6f);
    float4 wv4 = ((const float4*)w)[tid];
    float4 y;
    y.x = v.x * rinv * wv4.x; y.y = v.y * rinv * wv4.y;
    y.z = v.z * rinv * wv4.z; y.w = v.w * rinv * wv4.w;
    float mx = fmaxf(fmaxf(fabsf(y.x), fabsf(y.y)), fmaxf(fabsf(y.z), fabsf(y.w)));
    mx = waveMax(mx);
    if (lane == 0) red[wv] = mx;
    __syncthreads();
    float s = fmaxf(fmaxf(fmaxf(red[0], red[1]), fmaxf(red[2], red[3])), 1e-5f);
    if (tid == 0) xs[row] = s;
    float qf = 127.0f / s;
    char4 o;
    o.x = (signed char)(int)rintf(y.x * qf);
    o.y = (signed char)(int)rintf(y.y * qf);
    o.z = (signed char)(int)rintf(y.z * qf);
    o.w = (signed char)(int)rintf(y.w * qf);
    ((char4*)xq)[(size_t)row * 256 + tid] = o;
}

// ---------------- row quant only (K=4096) ----------------
__global__ __launch_bounds__(256) void qrow_k(const float* __restrict__ in,
                                              int8_t* __restrict__ q, float* __restrict__ xs) {
    __shared__ float red[4];
    int row = blockIdx.x, tid = threadIdx.x;
    const float4* xr = (const float4*)(in + (size_t)row * HIDF);
    float4 vv[4];
    float mx = 0.f;
#pragma unroll
    for (int j = 0; j < 4; ++j) {
        vv[j] = xr[j * 256 + tid];
        mx = fmaxf(mx, fmaxf(fmaxf(fabsf(vv[j].x), fabsf(vv[j].y)), fmaxf(fabsf(vv[j].z), fabsf(vv[j].w))));
    }
    mx = waveMax(mx);
    int lane = tid & 63, wv = tid >> 6;
    if (lane == 0) red[wv] = mx;
    __syncthreads();
    float s = fmaxf(fmaxf(fmaxf(red[0], red[1]), fmaxf(red[2], red[3])), 1e-5f);
    if (tid == 0) xs[row] = s;
    float qf = 127.0f / s;
#pragma unroll
    for (int j = 0; j < 4; ++j) {
        char4 o;
        o.x = (signed char)(int)rintf(vv[j].x * qf);
        o.y = (signed char)(int)rintf(vv[j].y * qf);
        o.z = (signed char)(int)rintf(vv[j].z * qf);
        o.w = (signed char)(int)rintf(vv[j].w * qf);
        ((char4*)q)[(size_t)row * 1024 + j * 256 + tid] = o;
    }
}

// ==================== int8 MFMA GEMM, 128x128 tile, BK=128, R8-proven core ====================
#define EPI_PLAIN 0
#define EPI_RESID 2

template <int EPI>
__global__ __launch_bounds__(256, 4) void gemm_i8(const int8_t* __restrict__ A,
                                                  const int8_t* __restrict__ B,
                                                  const float* __restrict__ xs,
                                                  const float* __restrict__ wsp,
                                                  const float* __restrict__ bias,
                                                  float* __restrict__ out,
                                                  int N, int K, int ldo) {
    __shared__ __align__(16) int8_t As[16384];
    __shared__ __align__(16) int8_t Bs[16384];
    const int tid = threadIdx.x;
    const int lane = tid & 63, wave = tid >> 6;
    const int wr = wave >> 1, wc = wave & 1;
    const int bm = blockIdx.x, bn = blockIdx.y;

    const int rA = tid >> 3;
    const int colb = (((tid & 7) ^ (rA & 7)) << 4);
    const int8_t* ap = A + (size_t)(bm * 128 + rA) * K + colb;
    const int8_t* bp = B + (size_t)(bn * 128 + rA) * K + colb;
    const size_t rstep = (size_t)32 * K;

    i32x4 acc[4][4] = {};
    const int fr = lane & 15, ks = lane >> 4;

    for (int kt = 0; kt < K; kt += 128) {
#pragma unroll
        for (int p = 0; p < 4; ++p) {
            gload16(ap + kt + (size_t)p * rstep, As + p * 4096 + tid * 16);
            gload16(bp + kt + (size_t)p * rstep, Bs + p * 4096 + tid * 16);
        }
        __syncthreads();
#pragma unroll
        for (int kh = 0; kh < 2; ++kh) {
            i32x4 af[4], bf[4];
#pragma unroll
            for (int m = 0; m < 4; ++m) {
                int ra = wr * 64 + m * 16 + fr;
                af[m] = *(const i32x4*)(As + ra * 128 + (((kh * 4 + ks) ^ (ra & 7)) << 4));
            }
#pragma unroll
            for (int n = 0; n < 4; ++n) {
                int rb = wc * 64 + n * 16 + fr;
                bf[n] = *(const i32x4*)(Bs + rb * 128 + (((kh * 4 + ks) ^ (rb & 7)) << 4));
            }
#pragma unroll
            for (int m = 0; m < 4; ++m)
#pragma unroll
                for (int n = 0; n < 4; ++n)
                    acc[m][n] = __builtin_amdgcn_mfma_i32_16x16x64_i8(af[m], bf[n], acc[m][n], 0, 0, 0);
        }
        __syncthreads();
    }

    const float ws = *wsp;
#pragma unroll
    for (int m = 0; m < 4; ++m) {
        int row0 = bm * 128 + wr * 64 + m * 16 + ks * 4;
#pragma unroll
        for (int n = 0; n < 4; ++n) {
            int col = bn * 128 + wc * 64 + n * 16 + fr;
            float bv = bias[col];
#pragma unroll
            for (int j = 0; j < 4; ++j) {
                int row = row0 + j;
                float v = (float)acc[m][n][j] * (xs[row] * ws * (1.0f / 127.0f)) + bv;
                size_t idx = (size_t)row * ldo + col;
                if (EPI == EPI_PLAIN) out[idx] = v;
                else                  out[idx] += v;   // EPI_RESID
            }
        }
    }
    (void)N;
}

// ---------------- gate GEMM + sigmoid + chunk-mean fused (R8-proven core) ----------------
__global__ __launch_bounds__(256, 4) void gate_decay(const int8_t* __restrict__ A,
                                                     const int8_t* __restrict__ B,
                                                     const float* __restrict__ xs,
                                                     const float* __restrict__ wsp,
                                                     const float* __restrict__ bias,
                                                     float* __restrict__ dec) {
    __shared__ __align__(16) int8_t As[16384];
    __shared__ __align__(16) int8_t Bs[16384];
    __shared__ float dsum[2][128];
    const int tid = threadIdx.x;
    const int lane = tid & 63, wave = tid >> 6;
    const int wr = wave >> 1, wc = wave & 1;
    const int bm = blockIdx.x, bn = blockIdx.y;
    const int K = 1024;

    const int rA = tid >> 3;
    const int colb = (((tid & 7) ^ (rA & 7)) << 4);
    const int8_t* ap = A + (size_t)(bm * 128 + rA) * K + colb;
    const int8_t* bp = B + (size_t)(bn * 128 + rA) * K + colb;
    const size_t rstep = (size_t)32 * K;

    i32x4 acc[4][4] = {};
    const int fr = lane & 15, ks = lane >> 4;

    for (int kt = 0; kt < K; kt += 128) {
#pragma unroll
        for (int p = 0; p < 4; ++p) {
            gload16(ap + kt + (size_t)p * rstep, As + p * 4096 + tid * 16);
            gload16(bp + kt + (size_t)p * rstep, Bs + p * 4096 + tid * 16);
        }
        __syncthreads();
#pragma unroll
        for (int kh = 0; kh < 2; ++kh) {
            i32x4 af[4], bf[4];
#pragma unroll
            for (int m = 0; m < 4; ++m) {
                int ra = wr * 64 + m * 16 + fr;
                af[m] = *(const i32x4*)(As + ra * 128 + (((kh * 4 + ks) ^ (ra & 7)) << 4));
            }
#pragma unroll
            for (int n = 0; n < 4; ++n) {
                int rb = wc * 64 + n * 16 + fr;
                bf[n] = *(const i32x4*)(Bs + rb * 128 + (((kh * 4 + ks) ^ (rb & 7)) << 4));
            }
#pragma unroll
            for (int m = 0; m < 4; ++m)
#pragma unroll
                for (int n = 0; n < 4; ++n)
                    acc[m][n] = __builtin_amdgcn_mfma_i32_16x16x64_i8(af[m], bf[n], acc[m][n], 0, 0, 0);
        }
        __syncthreads();
    }

    const float ws = *wsp;
#pragma unroll
    for (int n = 0; n < 4; ++n) {
        int col = bn * 128 + wc * 64 + n * 16 + fr;
        float bv = bias[col];
        float sn = 0.f;
#pragma unroll
        for (int m = 0; m < 4; ++m) {
            int row0 = bm * 128 + wr * 64 + m * 16 + ks * 4;
#pragma unroll
            for (int j = 0; j < 4; ++j) {
                int row = row0 + j;
                float v = (float)acc[m][n][j] * (xs[row] * ws * (1.0f / 127.0f)) + bv;
                sn += 1.0f / (1.0f + expf(-v));
            }
        }
        sn += __shfl_down(sn, 32);
        sn += __shfl_down(sn, 16);
        if (lane < 16) dsum[wr][wc * 64 + n * 16 + lane] = sn;
    }
    __syncthreads();
    if (tid < 128) {
        int b = bm >> 5, c = bm & 31;
        dec[(size_t)(c * 2 + b) * 1024 + bn * 128 + tid] =
            (dsum[0][tid] + dsum[1][tid]) * (1.0f / 128.0f);
    }
}

// ---------------- fc1: dual-B GEMM + SwiGLU, 128x64 tile, T3/T4 counted-vmcnt pipeline ------
// 2 buffers x BK=64, stage 2 tiles ahead. Raw s_barrier; vmcnt(4) mid-loop (never 0);
// restage only after all waves' lgkmcnt(0)+barrier. 32KB LDS -> 4 blocks/CU kept.
__global__ __launch_bounds__(256, 4) void gemm_fc1(const int8_t* __restrict__ A,
                                                   const int8_t* __restrict__ B1,
                                                   const int8_t* __restrict__ B2,
                                                   const float* __restrict__ xs,
                                                   const float* __restrict__ wsp,
                                                   const float* __restrict__ bias,
                                                   float* __restrict__ out) {
    __shared__ __align__(16) int8_t As[2][8192];
    __shared__ __align__(16) int8_t Bs1[2][4096];
    __shared__ __align__(16) int8_t Bs2[2][4096];
    const int tid = threadIdx.x;
    const int lane = tid & 63, wave = tid >> 6;
    const int wr = wave >> 1, wc = wave & 1;   // 2x2 waves over (128 rows, 64 cols)
    const int bm = blockIdx.x, bn = blockIdx.y;
    const int K = 1024;

    const int r0 = tid >> 2, sl = tid & 3;           // r0 in [0,64)
    const int c0 = ((sl ^ ((r0 >> 1) & 3)) << 4);
    const int r1 = r0 + 64;
    const int8_t* a0  = A  + (size_t)(bm * 128 + r0) * K + c0;
    const int8_t* a1  = A  + (size_t)(bm * 128 + r1) * K + c0;
    const int8_t* b1p = B1 + (size_t)(bn * 64 + r0) * K + c0;   // 64-row B tiles
    const int8_t* b2p = B2 + (size_t)(bn * 64 + r0) * K + c0;

    i32x4 acc1[4][2] = {}, acc2[4][2] = {};
    const int fr = lane & 15, ks = lane >> 4;

#define STAGE_FC1(buf, kt_)  do {                         \
        gload16(a0  + (kt_), As[buf] + tid * 16);         \
        gload16(a1  + (kt_), As[buf] + 4096 + tid * 16);  \
        gload16(b1p + (kt_), Bs1[buf] + tid * 16);        \
        gload16(b2p + (kt_), Bs2[buf] + tid * 16);        \
    } while (0)

    // prologue: tiles 0 and 1 in flight (8 loads)
    STAGE_FC1(0, 0);
    STAGE_FC1(1, 64);

    const int NT = 16;   // K / 64
    for (int t = 0; t < NT; ++t) {
        const int cur = t & 1;
        // oldest 4 outstanding loads are buf[cur]'s (issued at t-2 / prologue)
        if (t < NT - 1) asm volatile("s_waitcnt vmcnt(4)" ::: "memory");
        else            asm volatile("s_waitcnt vmcnt(0)" ::: "memory");
        __builtin_amdgcn_s_barrier();          // buf[cur] visible to all waves
        i32x4 af[4], b1f[2], b2f[2];
#pragma unroll
        for (int m = 0; m < 4; ++m) {
            int ra = wr * 64 + m * 16 + fr;
            af[m] = *(const i32x4*)(As[cur] + ra * 64 + ((ks ^ ((ra >> 1) & 3)) << 4));
        }
#pragma unroll
        for (int n = 0; n < 2; ++n) {
            int rb = wc * 32 + n * 16 + fr;
            int off = rb * 64 + ((ks ^ ((rb >> 1) & 3)) << 4);
            b1f[n] = *(const i32x4*)(Bs1[cur] + off);
            b2f[n] = *(const i32x4*)(Bs2[cur] + off);
        }
        asm volatile("s_waitcnt lgkmcnt(0)" ::: "memory");   // my reads of buf[cur] complete
        __builtin_amdgcn_s_barrier();          // ALL waves done reading buf[cur]
        __builtin_amdgcn_sched_barrier(0);     // pin restage below the barrier
        if (t + 2 < NT) STAGE_FC1(cur, (t + 2) * 64);        // safe to overwrite buf[cur]
#pragma unroll
        for (int m = 0; m < 4; ++m)
#pragma unroll
            for (int n = 0; n < 2; ++n) {
                acc1[m][n] = __builtin_amdgcn_mfma_i32_16x16x64_i8(af[m], b1f[n], acc1[m][n], 0, 0, 0);
                acc2[m][n] = __builtin_amdgcn_mfma_i32_16x16x64_i8(af[m], b2f[n], acc2[m][n], 0, 0, 0);
            }
    }
#undef STAGE_FC1

    const float ws = *wsp;
#pragma unroll
    for (int m = 0; m < 4; ++m) {
        int row0 = bm * 128 + wr * 64 + m * 16 + ks * 4;
#pragma unroll
        for (int n = 0; n < 2; ++n) {
            int col = bn * 64 + wc * 32 + n * 16 + fr;
            float ba = bias[col];
            float bg = bias[col + 4096];
#pragma unroll
            for (int j = 0; j < 4; ++j) {
                int row = row0 + j;
                float sc = xs[row] * ws * (1.0f / 127.0f);
                float a = (float)acc1[m][n][j] * sc + ba;
                float g = (float)acc2[m][n][j] * sc + bg;
                out[(size_t)row * HIDF + col] = a * g / (1.0f + expf(-g));
            }
        }
    }
}

// ---------------- per-token head-mix softmax attention (rope fused on q,k) ----------------
__global__ __launch_bounds__(256) void attn_intra(const float* __restrict__ qkv,
                                                  const float* __restrict__ ct,
                                                  const float* __restrict__ st,
                                                  float* __restrict__ o) {
    __shared__ float q_s[1024], k_s[1024], v_s[1024], p_s[256];
    int t = blockIdx.x, tid = threadIdx.x;
    int n = t & (SEQ - 1);
    int j0 = (tid & 15) * 2;
    const float4* src = (const float4*)(qkv + (size_t)t * 3072);
    ((float4*)q_s)[tid] = rope4(src[tid], ct, st, n, j0);
    ((float4*)k_s)[tid] = rope4(src[256 + tid], ct, st, n, j0);
    ((float4*)v_s)[tid] = src[512 + tid];
    __syncthreads();
    int h = tid >> 4, g = tid & 15;
    const float4* q4 = (const float4*)q_s + h * 16;
    const float4* k4 = (const float4*)k_s + g * 16;
    float accS = 0.f;
#pragma unroll
    for (int i = 0; i < 16; ++i) {
        float4 qa = q4[i], ka = k4[i];
        accS += qa.x * ka.x + qa.y * ka.y + qa.z * ka.z + qa.w * ka.w;
    }
    accS *= 0.125f;
    float mx = accS;
#pragma unroll
    for (int o2 = 8; o2 >= 1; o2 >>= 1) mx = fmaxf(mx, __shfl_xor(mx, o2, 16));
    float e = expf(accS - mx);
    float sm = e;
#pragma unroll
    for (int o2 = 8; o2 >= 1; o2 >>= 1) sm += __shfl_xor(sm, o2, 16);
    p_s[tid] = e / sm;
    __syncthreads();
    int dq = tid & 15;
    float4 acc = {0.f, 0.f, 0.f, 0.f};
    const float4* v4 = (const float4*)v_s;
#pragma unroll
    for (int gg = 0; gg < 16; ++gg) {
        float p = p_s[h * 16 + gg];
        float4 vv = v4[gg * 16 + dq];
        acc.x += p * vv.x; acc.y += p * vv.y; acc.z += p * vv.z; acc.w += p * vv.w;
    }
    ((float4*)(o + (size_t)t * DIMC))[h * 16 + dq] = acc;
}

// ---------------- per-chunk outer product U = k^T v (rope fused on k) ----------------
__global__ __launch_bounds__(256) void u_k(const float* __restrict__ qkv,
                                           const float* __restrict__ ct,
                                           const float* __restrict__ st,
                                           float* __restrict__ U) {
    __shared__ float ks_[8192], vs_[8192];
    int bid = blockIdx.x, tid = threadIdx.x;
    int c = bid >> 5, b = (bid >> 4) & 1, h = bid & 15;
    size_t tok = (size_t)(b * SEQ + c * CHUNKL);
#pragma unroll
    for (int j = 0; j < 8; ++j) {
        int idx = j * 256 + tid;
        int l = idx >> 4, c4 = idx & 15;
        int n = (int)((tok + l) & (SEQ - 1));
        const float* kp = qkv + (tok + l) * 3072 + 1024 + h * 64 + c4 * 4;
        const float* vp = qkv + (tok + l) * 3072 + 2048 + h * 64 + c4 * 4;
        ((float4*)ks_)[idx] = rope4(*(const float4*)kp, ct, st, n, c4 * 2);
        ((float4*)vs_)[idx] = *(const float4*)vp;
    }
    __syncthreads();
    int d = tid >> 2, eg = tid & 3;
    float4 acc[4] = {};
    for (int l = 0; l < CHUNKL; ++l) {
        float kd = ks_[l * 64 + d];
        const float4* vrow = (const float4*)(vs_ + l * 64) + eg * 4;
#pragma unroll
        for (int i = 0; i < 4; ++i) {
            float4 vv = vrow[i];
            acc[i].x += kd * vv.x; acc[i].y += kd * vv.y;
            acc[i].z += kd * vv.z; acc[i].w += kd * vv.w;
        }
    }
    float4* Up = (float4*)(U + (size_t)bid * 4096) + d * 16 + eg * 4;
#pragma unroll
    for (int i = 0; i < 4; ++i) Up[i] = acc[i];
}

// ---------------- diagonal-decay scan over chunks ----------------
__global__ __launch_bounds__(256) void scan_k(const float* __restrict__ U,
                                              const float* __restrict__ dec,
                                              float* __restrict__ kvprev) {
    int t = blockIdx.x * 256 + threadIdx.x;   // 131072
    int b = t >> 16;
    int h = (t >> 12) & 15;
    int d = (t >> 6) & 63;
    float val = 0.f;
#pragma unroll 1
    for (int c = 0; c < NCHUNK; ++c) {
        kvprev[(size_t)c * 131072 + t] = val;
        val = val * dec[(c * 2 + b) * 1024 + h * 64 + d] + U[(size_t)c * 131072 + t];
    }
}

// ---------------- out += q @ kv_prev (rope fused on q) ----------------
__global__ __launch_bounds__(256) void out2_k(const float* __restrict__ qkv,
                                              const float* __restrict__ ct,
                                              const float* __restrict__ st,
                                              const float* __restrict__ kvprev,
                                              float* __restrict__ o) {
    __shared__ float kv_s[4096];
    __shared__ float q_s[128 * 65];
    int bid = blockIdx.x, tid = threadIdx.x;
    int c = bid >> 5, b = (bid >> 4) & 1, h = bid & 15;
    size_t tok = (size_t)(b * SEQ + c * CHUNKL);
    const float4* kvsrc = (const float4*)(kvprev + (size_t)c * 131072 + b * 65536 + h * 4096);
#pragma unroll
    for (int j = 0; j < 4; ++j) ((float4*)kv_s)[j * 256 + tid] = kvsrc[j * 256 + tid];
#pragma unroll
    for (int j = 0; j < 8; ++j) {
        int idx = j * 256 + tid;
        int l = idx >> 4, c4 = idx & 15;
        int n = (int)((tok + l) & (SEQ - 1));
        float4 qv = rope4(*(const float4*)(qkv + (tok + l) * 3072 + h * 64 + c4 * 4),
                          ct, st, n, c4 * 2);
        float* dq = q_s + l * 65 + c4 * 4;
        dq[0] = qv.x; dq[1] = qv.y; dq[2] = qv.z; dq[3] = qv.w;
    }
    __syncthreads();
    int l = tid >> 1, eh = tid & 1;
    float4 acc[8] = {};
    const float* qrow = q_s + l * 65;
    for (int d = 0; d < 64; ++d) {
        float qd = qrow[d];
        const float4* kvr = (const float4*)(kv_s + d * 64) + eh * 8;
#pragma unroll
        for (int i = 0; i < 8; ++i) {
            float4 kk = kvr[i];
            acc[i].x += qd * kk.x; acc[i].y += qd * kk.y;
            acc[i].z += qd * kk.z; acc[i].w += qd * kk.w;
        }
    }
    float4* op = (float4*)(o + (tok + l) * DIMC + h * 64 + eh * 32);
#pragma unroll
    for (int i = 0; i < 8; ++i) {
        float4 cur = op[i];
        cur.x += acc[i].x; cur.y += acc[i].y; cur.z += acc[i].z; cur.w += acc[i].w;
        op[i] = cur;
    }
}

// =====================================================================
extern "C" void kernel_launch(void* const* d_in, const int* in_sizes, int n_in,
                              void* d_out, int out_size, void* d_ws, size_t ws_size,
                              hipStream_t stream) {
    const float* x_in       = (const float*)d_in[0];
    const float* norm1_w    = (const float*)d_in[1];
    const float* qkv_w      = (const float*)d_in[2];
    const float* qkv_b      = (const float*)d_in[3];
    const float* gate_w     = (const float*)d_in[4];
    const float* gate_b     = (const float*)d_in[5];
    const float* proj_w     = (const float*)d_in[6];
    const float* proj_b     = (const float*)d_in[7];
    const float* attn_norm_w= (const float*)d_in[8];
    const float* norm2_w    = (const float*)d_in[9];
    const float* fc1_w      = (const float*)d_in[10];
    const float* fc1_b      = (const float*)d_in[11];
    const float* fc2_w      = (const float*)d_in[12];
    const float* fc2_b      = (const float*)d_in[13];
    float* x = (float*)d_out;

    char* wsb = (char*)d_ws;
    size_t off = 0;
    auto carve = [&](size_t bytes) { char* p = wsb + off; off = (off + bytes + 255) & ~(size_t)255; return p; };
    int8_t* q_qkv  = (int8_t*)carve(12582912);
    int8_t* q_gate = (int8_t*)carve(4194304);
    int8_t* q_proj = (int8_t*)carve(4194304);
    int8_t* q_fc1  = (int8_t*)carve(33554432);
    int8_t* q_fc2  = (int8_t*)carve(16777216);
    float*  wsc    = (float*)carve(256);
    float*  part   = (float*)carve(4096);
    float*  ropec  = (float*)carve(524288);
    float*  ropes  = (float*)carve(524288);
    int8_t* qbuf   = (int8_t*)carve(33554432);
    float*  xsbuf  = (float*)carve(32768);
    float*  big    = (float*)carve(134217728);   // qkv(100MB) / fc1-mid(134MB)
    float*  attn_o = (float*)carve(33554432);
    float*  Ub     = (float*)carve(16777216);
    float*  kvprev = (float*)carve(16777216);
    float*  decayb = (float*)carve(262144);
    (void)ws_size; (void)in_sizes; (void)n_in; (void)out_size;

    hipMemcpyAsync(x, x_in, (size_t)NTOK * DIMC * sizeof(float), hipMemcpyDeviceToDevice, stream);
    ropetab_k<<<512, 256, 0, stream>>>(ropec, ropes);

    struct WSpec { const float* w; int8_t* q; int perlayer; int arr; };
    WSpec specs[5] = {
        {qkv_w,  q_qkv,  3 * DIMC * DIMC, 0},
        {gate_w, q_gate, DIMC * DIMC,     1},
        {proj_w, q_proj, DIMC * DIMC,     2},
        {fc1_w,  q_fc1,  8192 * 1024,     3},
        {fc2_w,  q_fc2,  DIMC * HIDF,     4},
    };
    for (int a = 0; a < 5; ++a) {
        prep_k<<<dim3(256, NLAYERS), 256, 0, stream>>>(specs[a].w, specs[a].q, part, specs[a].perlayer / 4);
        amean_fin<<<NLAYERS, 256, 0, stream>>>(part, wsc + specs[a].arr * 4, specs[a].perlayer);
    }

    for (int l = 0; l < NLAYERS; ++l) {
        // ---- attention ----
        rmsq_k<<<NTOK, 256, 0, stream>>>(x, norm1_w + l * DIMC, qbuf, xsbuf);
        gemm_i8<EPI_PLAIN><<<dim3(64, 24), 256, 0, stream>>>(
            qbuf, q_qkv + (size_t)l * 3145728, xsbuf, wsc + 0 * 4 + l,
            qkv_b + l * 3072, big, 3072, 1024, 3072);
        gate_decay<<<dim3(64, 8), 256, 0, stream>>>(
            qbuf, q_gate + (size_t)l * 1048576, xsbuf, wsc + 1 * 4 + l,
            gate_b + l * DIMC, decayb);
        attn_intra<<<NTOK, 256, 0, stream>>>(big, ropec, ropes, attn_o);
        u_k<<<1024, 256, 0, stream>>>(big, ropec, ropes, Ub);
        scan_k<<<512, 256, 0, stream>>>(Ub, decayb, kvprev);
        out2_k<<<1024, 256, 0, stream>>>(big, ropec, ropes, kvprev, attn_o);
        rmsq_k<<<NTOK, 256, 0, stream>>>(attn_o, attn_norm_w + l * DIMC, qbuf, xsbuf);
        gemm_i8<EPI_RESID><<<dim3(64, 8), 256, 0, stream>>>(
            qbuf, q_proj + (size_t)l * 1048576, xsbuf, wsc + 2 * 4 + l,
            proj_b + l * DIMC, x, 1024, 1024, 1024);
        // ---- mlp ----
        rmsq_k<<<NTOK, 256, 0, stream>>>(x, norm2_w + l * DIMC, qbuf, xsbuf);
        gemm_fc1<<<dim3(64, 64), 256, 0, stream>>>(
            qbuf, q_fc1 + (size_t)l * 8388608, q_fc1 + (size_t)l * 8388608 + 4194304,
            xsbuf, wsc + 3 * 4 + l, fc1_b + l * 8192, big);
        qrow_k<<<NTOK, 256, 0, stream>>>(big, qbuf, xsbuf);
        gemm_i8<EPI_RESID><<<dim3(64, 8), 256, 0, stream>>>(
            qbuf, q_fc2 + (size_t)l * 4194304, xsbuf, wsc + 4 * 4 + l,
            fc2_b + l * DIMC, x, 1024, 4096, 1024);
    }
}

// Round 11
// 1873.840 us; speedup vs baseline: 1.1451x; 1.0804x over previous
//
#include <hip/hip_runtime.h>
#include <hip/hip_bf16.h>
#include <cstdint>
#include <cstddef>

#define NLAYERS 4
#define SEQ     4096
#define DIMC    1024
#define CHUNKL  128
#define NCHUNK  32
#define HIDF    4096
#define NTOK    8192

using i32x4 = __attribute__((ext_vector_type(4))) int;
typedef _Float16 half4v __attribute__((ext_vector_type(4)));

__device__ __forceinline__ float4 h4f(half4v h) {
    float4 r; r.x = (float)h[0]; r.y = (float)h[1]; r.z = (float)h[2]; r.w = (float)h[3];
    return r;
}

__device__ __forceinline__ void gload16(const void* g, void* l) {
    __builtin_amdgcn_global_load_lds((const __attribute__((address_space(1))) void*)g,
                                     (__attribute__((address_space(3))) void*)l, 16, 0, 0);
}

__device__ __forceinline__ float waveSum(float v) {
#pragma unroll
    for (int o = 32; o >= 1; o >>= 1) v += __shfl_down(v, o);
    return v;
}
__device__ __forceinline__ float waveMax(float v) {
#pragma unroll
    for (int o = 32; o >= 1; o >>= 1) v = fmaxf(v, __shfl_down(v, o));
    return v;
}

// ---------------- weight prep: |w| partial sums + sign quant in ONE pass ----------------
__global__ __launch_bounds__(256) void prep_k(const float* __restrict__ w, int8_t* __restrict__ q,
                                              float* __restrict__ part, int perlayer4) {
    __shared__ float red[4];
    int blk = blockIdx.x, layer = blockIdx.y, tid = threadIdx.x;
    const float4* p = (const float4*)(w + (size_t)layer * perlayer4 * 4);
    char4* qp = (char4*)(q + (size_t)layer * perlayer4 * 4);
    float s = 0.f;
    for (int i = blk * 256 + tid; i < perlayer4; i += 256 * 256) {
        float4 v = p[i];
        s += fabsf(v.x) + fabsf(v.y) + fabsf(v.z) + fabsf(v.w);
        char4 o;
        o.x = (v.x > 0.f) ? 1 : ((v.x < 0.f) ? -1 : 0);
        o.y = (v.y > 0.f) ? 1 : ((v.y < 0.f) ? -1 : 0);
        o.z = (v.z > 0.f) ? 1 : ((v.z < 0.f) ? -1 : 0);
        o.w = (v.w > 0.f) ? 1 : ((v.w < 0.f) ? -1 : 0);
        qp[i] = o;
    }
    s = waveSum(s);
    int lane = tid & 63, wv = tid >> 6;
    if (lane == 0) red[wv] = s;
    __syncthreads();
    if (tid == 0) part[layer * 256 + blk] = red[0] + red[1] + red[2] + red[3];
}

__global__ __launch_bounds__(256) void amean_fin(const float* __restrict__ part,
                                                 float* __restrict__ wsc, int perlayer) {
    __shared__ float red[4];
    int layer = blockIdx.x, tid = threadIdx.x;
    float s = part[layer * 256 + tid];
    s = waveSum(s);
    int lane = tid & 63, wv = tid >> 6;
    if (lane == 0) red[wv] = s;
    __syncthreads();
    if (tid == 0) {
        float tot = red[0] + red[1] + red[2] + red[3];
        wsc[layer] = fmaxf(tot / (float)perlayer, 1e-5f);
    }
}

// ---------------- rope tables ----------------
__global__ __launch_bounds__(256) void ropetab_k(float* __restrict__ ct, float* __restrict__ st) {
    int i = blockIdx.x * 256 + threadIdx.x;   // SEQ*32
    int n = i >> 5, j = i & 31;
    float inv = exp2f(-(float)j * (13.287712379549449f / 32.0f)); // 10000^(-j/32)
    float f = (float)n * inv;
    ct[i] = cosf(f);
    st[i] = sinf(f);
}

// rotate a float4 (two rope pairs)
__device__ __forceinline__ float4 rope4(float4 v, const float* ct, const float* st, int n, int j0) {
    float c0 = ct[n * 32 + j0], s0 = st[n * 32 + j0];
    float c1 = ct[n * 32 + j0 + 1], s1 = st[n * 32 + j0 + 1];
    float4 r;
    r.x = v.x * c0 - v.y * s0;
    r.y = v.x * s0 + v.y * c0;
    r.z = v.z * c1 - v.w * s1;
    r.w = v.z * s1 + v.w * c1;
    return r;
}

// ---------------- rmsnorm + row quant (K=1024, f32 input) ----------------
__global__ __launch_bounds__(256) void rmsq_k(const float* __restrict__ x, const float* __restrict__ w,
                                              int8_t* __restrict__ xq, float* __restrict__ xs) {
    __shared__ float red[4];
    int row = blockIdx.x, tid = threadIdx.x;
    const float4* xr = (const float4*)(x + (size_t)row * DIMC);
    float4 v = xr[tid];
    float ss = v.x * v.x + v.y * v.y + v.z * v.z + v.w * v.w;
    ss = waveSum(ss);
    int lane = tid & 63, wv = tid >> 6;
    if (lane == 0) red[wv] = ss;
    __syncthreads();
    float tot = red[0] + red[1] + red[2] + red[3];
    __syncthreads();
    float rinv = 1.0f / sqrtf(tot * (1.0f / (float)DIMC) + 1e-6f);
    float4 wv4 = ((const float4*)w)[tid];
    float4 y;
    y.x = v.x * rinv * wv4.x; y.y = v.y * rinv * wv4.y;
    y.z = v.z * rinv * wv4.z; y.w = v.w * rinv * wv4.w;
    float mx = fmaxf(fmaxf(fabsf(y.x), fabsf(y.y)), fmaxf(fabsf(y.z), fabsf(y.w)));
    mx = waveMax(mx);
    if (lane == 0) red[wv] = mx;
    __syncthreads();
    float s = fmaxf(fmaxf(fmaxf(red[0], red[1]), fmaxf(red[2], red[3])), 1e-5f);
    if (tid == 0) xs[row] = s;
    float qf = 127.0f / s;
    char4 o;
    o.x = (signed char)(int)rintf(y.x * qf);
    o.y = (signed char)(int)rintf(y.y * qf);
    o.z = (signed char)(int)rintf(y.z * qf);
    o.w = (signed char)(int)rintf(y.w * qf);
    ((char4*)xq)[(size_t)row * 256 + tid] = o;
}

// ---------------- row quant only (K=4096, f16 input) ----------------
__global__ __launch_bounds__(256) void qrow_k(const _Float16* __restrict__ in,
                                              int8_t* __restrict__ q, float* __restrict__ xs) {
    __shared__ float red[4];
    int row = blockIdx.x, tid = threadIdx.x;
    const half4v* xr = (const half4v*)(in + (size_t)row * HIDF);
    float4 vv[4];
    float mx = 0.f;
#pragma unroll
    for (int j = 0; j < 4; ++j) {
        vv[j] = h4f(xr[j * 256 + tid]);
        mx = fmaxf(mx, fmaxf(fmaxf(fabsf(vv[j].x), fabsf(vv[j].y)), fmaxf(fabsf(vv[j].z), fabsf(vv[j].w))));
    }
    mx = waveMax(mx);
    int lane = tid & 63, wv = tid >> 6;
    if (lane == 0) red[wv] = mx;
    __syncthreads();
    float s = fmaxf(fmaxf(fmaxf(red[0], red[1]), fmaxf(red[2], red[3])), 1e-5f);
    if (tid == 0) xs[row] = s;
    float qf = 127.0f / s;
#pragma unroll
    for (int j = 0; j < 4; ++j) {
        char4 o;
        o.x = (signed char)(int)rintf(vv[j].x * qf);
        o.y = (signed char)(int)rintf(vv[j].y * qf);
        o.z = (signed char)(int)rintf(vv[j].z * qf);
        o.w = (signed char)(int)rintf(vv[j].w * qf);
        ((char4*)q)[(size_t)row * 1024 + j * 256 + tid] = o;
    }
}

// ==================== int8 MFMA GEMM, 128x128 tile, BK=128, R8-proven core ====================
#define EPI_PLANH 1
#define EPI_RESID 2

template <int EPI>
__global__ __launch_bounds__(256, 4) void gemm_i8(const int8_t* __restrict__ A,
                                                  const int8_t* __restrict__ B,
                                                  const float* __restrict__ xs,
                                                  const float* __restrict__ wsp,
                                                  const float* __restrict__ bias,
                                                  float* __restrict__ out,
                                                  int N, int K, int ldo) {
    __shared__ __align__(16) int8_t As[16384];
    __shared__ __align__(16) int8_t Bs[16384];
    const int tid = threadIdx.x;
    const int lane = tid & 63, wave = tid >> 6;
    const int wr = wave >> 1, wc = wave & 1;
    const int bm = blockIdx.x, bn = blockIdx.y;

    const int rA = tid >> 3;
    const int colb = (((tid & 7) ^ (rA & 7)) << 4);
    const int8_t* ap = A + (size_t)(bm * 128 + rA) * K + colb;
    const int8_t* bp = B + (size_t)(bn * 128 + rA) * K + colb;
    const size_t rstep = (size_t)32 * K;

    i32x4 acc[4][4] = {};
    const int fr = lane & 15, ks = lane >> 4;

    for (int kt = 0; kt < K; kt += 128) {
#pragma unroll
        for (int p = 0; p < 4; ++p) {
            gload16(ap + kt + (size_t)p * rstep, As + p * 4096 + tid * 16);
            gload16(bp + kt + (size_t)p * rstep, Bs + p * 4096 + tid * 16);
        }
        __syncthreads();
#pragma unroll
        for (int kh = 0; kh < 2; ++kh) {
            i32x4 af[4], bf[4];
#pragma unroll
            for (int m = 0; m < 4; ++m) {
                int ra = wr * 64 + m * 16 + fr;
                af[m] = *(const i32x4*)(As + ra * 128 + (((kh * 4 + ks) ^ (ra & 7)) << 4));
            }
#pragma unroll
            for (int n = 0; n < 4; ++n) {
                int rb = wc * 64 + n * 16 + fr;
                bf[n] = *(const i32x4*)(Bs + rb * 128 + (((kh * 4 + ks) ^ (rb & 7)) << 4));
            }
#pragma unroll
            for (int m = 0; m < 4; ++m)
#pragma unroll
                for (int n = 0; n < 4; ++n)
                    acc[m][n] = __builtin_amdgcn_mfma_i32_16x16x64_i8(af[m], bf[n], acc[m][n], 0, 0, 0);
        }
        __syncthreads();
    }

    const float ws = *wsp;
#pragma unroll
    for (int m = 0; m < 4; ++m) {
        int row0 = bm * 128 + wr * 64 + m * 16 + ks * 4;
#pragma unroll
        for (int n = 0; n < 4; ++n) {
            int col = bn * 128 + wc * 64 + n * 16 + fr;
            float bv = bias[col];
#pragma unroll
            for (int j = 0; j < 4; ++j) {
                int row = row0 + j;
                float v = (float)acc[m][n][j] * (xs[row] * ws * (1.0f / 127.0f)) + bv;
                size_t idx = (size_t)row * ldo + col;
                if (EPI == EPI_PLANH) ((_Float16*)out)[idx] = (_Float16)v;
                else                  out[idx] += v;   // EPI_RESID (f32)
            }
        }
    }
    (void)N;
}

// ---------------- gate GEMM + sigmoid + chunk-mean fused (R8-proven core) ----------------
__global__ __launch_bounds__(256, 4) void gate_decay(const int8_t* __restrict__ A,
                                                     const int8_t* __restrict__ B,
                                                     const float* __restrict__ xs,
                                                     const float* __restrict__ wsp,
                                                     const float* __restrict__ bias,
                                                     float* __restrict__ dec) {
    __shared__ __align__(16) int8_t As[16384];
    __shared__ __align__(16) int8_t Bs[16384];
    __shared__ float dsum[2][128];
    const int tid = threadIdx.x;
    const int lane = tid & 63, wave = tid >> 6;
    const int wr = wave >> 1, wc = wave & 1;
    const int bm = blockIdx.x, bn = blockIdx.y;
    const int K = 1024;

    const int rA = tid >> 3;
    const int colb = (((tid & 7) ^ (rA & 7)) << 4);
    const int8_t* ap = A + (size_t)(bm * 128 + rA) * K + colb;
    const int8_t* bp = B + (size_t)(bn * 128 + rA) * K + colb;
    const size_t rstep = (size_t)32 * K;

    i32x4 acc[4][4] = {};
    const int fr = lane & 15, ks = lane >> 4;

    for (int kt = 0; kt < K; kt += 128) {
#pragma unroll
        for (int p = 0; p < 4; ++p) {
            gload16(ap + kt + (size_t)p * rstep, As + p * 4096 + tid * 16);
            gload16(bp + kt + (size_t)p * rstep, Bs + p * 4096 + tid * 16);
        }
        __syncthreads();
#pragma unroll
        for (int kh = 0; kh < 2; ++kh) {
            i32x4 af[4], bf[4];
#pragma unroll
            for (int m = 0; m < 4; ++m) {
                int ra = wr * 64 + m * 16 + fr;
                af[m] = *(const i32x4*)(As + ra * 128 + (((kh * 4 + ks) ^ (ra & 7)) << 4));
            }
#pragma unroll
            for (int n = 0; n < 4; ++n) {
                int rb = wc * 64 + n * 16 + fr;
                bf[n] = *(const i32x4*)(Bs + rb * 128 + (((kh * 4 + ks) ^ (rb & 7)) << 4));
            }
#pragma unroll
            for (int m = 0; m < 4; ++m)
#pragma unroll
                for (int n = 0; n < 4; ++n)
                    acc[m][n] = __builtin_amdgcn_mfma_i32_16x16x64_i8(af[m], bf[n], acc[m][n], 0, 0, 0);
        }
        __syncthreads();
    }

    const float ws = *wsp;
#pragma unroll
    for (int n = 0; n < 4; ++n) {
        int col = bn * 128 + wc * 64 + n * 16 + fr;
        float bv = bias[col];
        float sn = 0.f;
#pragma unroll
        for (int m = 0; m < 4; ++m) {
            int row0 = bm * 128 + wr * 64 + m * 16 + ks * 4;
#pragma unroll
            for (int j = 0; j < 4; ++j) {
                int row = row0 + j;
                float v = (float)acc[m][n][j] * (xs[row] * ws * (1.0f / 127.0f)) + bv;
                sn += 1.0f / (1.0f + expf(-v));
            }
        }
        sn += __shfl_down(sn, 32);
        sn += __shfl_down(sn, 16);
        if (lane < 16) dsum[wr][wc * 64 + n * 16 + lane] = sn;
    }
    __syncthreads();
    if (tid < 128) {
        int b = bm >> 5, c = bm & 31;
        dec[(size_t)(c * 2 + b) * 1024 + bn * 128 + tid] =
            (dsum[0][tid] + dsum[1][tid]) * (1.0f / 128.0f);
    }
}

// ---------------- fc1 fused dual-B GEMM + SwiGLU, 128x64 tile, BK=128 (R8 core), f16 out ----
__global__ __launch_bounds__(256, 4) void gemm_fc1(const int8_t* __restrict__ A,
                                                   const int8_t* __restrict__ B1,
                                                   const int8_t* __restrict__ B2,
                                                   const float* __restrict__ xs,
                                                   const float* __restrict__ wsp,
                                                   const float* __restrict__ bias,
                                                   _Float16* __restrict__ out) {
    __shared__ __align__(16) int8_t As[16384];
    __shared__ __align__(16) int8_t Bs1[8192];
    __shared__ __align__(16) int8_t Bs2[8192];
    const int tid = threadIdx.x;
    const int lane = tid & 63, wave = tid >> 6;
    const int wr = wave >> 1, wc = wave & 1;   // 2x2 waves over (128 rows, 64 cols)
    const int bm = blockIdx.x, bn = blockIdx.y;
    const int K = 1024;

    const int rA = tid >> 3;                         // [0,32)
    const int colb = (((tid & 7) ^ (rA & 7)) << 4);
    const int8_t* ap  = A  + (size_t)(bm * 128 + rA) * K + colb;
    const int8_t* b1p = B1 + (size_t)(bn * 64 + rA) * K + colb;
    const int8_t* b2p = B2 + (size_t)(bn * 64 + rA) * K + colb;
    const size_t rstep = (size_t)32 * K;

    i32x4 acc1[4][2] = {}, acc2[4][2] = {};
    const int fr = lane & 15, ks = lane >> 4;

    for (int kt = 0; kt < K; kt += 128) {
#pragma unroll
        for (int p = 0; p < 4; ++p)
            gload16(ap + kt + (size_t)p * rstep, As + p * 4096 + tid * 16);
#pragma unroll
        for (int p = 0; p < 2; ++p) {
            gload16(b1p + kt + (size_t)p * rstep, Bs1 + p * 4096 + tid * 16);
            gload16(b2p + kt + (size_t)p * rstep, Bs2 + p * 4096 + tid * 16);
        }
        __syncthreads();
#pragma unroll
        for (int kh = 0; kh < 2; ++kh) {
            i32x4 af[4], b1f[2], b2f[2];
#pragma unroll
            for (int m = 0; m < 4; ++m) {
                int ra = wr * 64 + m * 16 + fr;
                af[m] = *(const i32x4*)(As + ra * 128 + (((kh * 4 + ks) ^ (ra & 7)) << 4));
            }
#pragma unroll
            for (int n = 0; n < 2; ++n) {
                int rb = wc * 32 + n * 16 + fr;      // [0,64)
                int off = rb * 128 + (((kh * 4 + ks) ^ (rb & 7)) << 4);
                b1f[n] = *(const i32x4*)(Bs1 + off);
                b2f[n] = *(const i32x4*)(Bs2 + off);
            }
#pragma unroll
            for (int m = 0; m < 4; ++m)
#pragma unroll
                for (int n = 0; n < 2; ++n) {
                    acc1[m][n] = __builtin_amdgcn_mfma_i32_16x16x64_i8(af[m], b1f[n], acc1[m][n], 0, 0, 0);
                    acc2[m][n] = __builtin_amdgcn_mfma_i32_16x16x64_i8(af[m], b2f[n], acc2[m][n], 0, 0, 0);
                }
        }
        __syncthreads();
    }

    const float ws = *wsp;
#pragma unroll
    for (int m = 0; m < 4; ++m) {
        int row0 = bm * 128 + wr * 64 + m * 16 + ks * 4;
#pragma unroll
        for (int n = 0; n < 2; ++n) {
            int col = bn * 64 + wc * 32 + n * 16 + fr;
            float ba = bias[col];
            float bg = bias[col + 4096];
#pragma unroll
            for (int j = 0; j < 4; ++j) {
                int row = row0 + j;
                float sc = xs[row] * ws * (1.0f / 127.0f);
                float a = (float)acc1[m][n][j] * sc + ba;
                float g = (float)acc2[m][n][j] * sc + bg;
                out[(size_t)row * HIDF + col] = (_Float16)(a * g / (1.0f + expf(-g)));
            }
        }
    }
}

// ---------------- per-token head-mix softmax attention (f16 qkv in, rope fused) ----------------
__global__ __launch_bounds__(256) void attn_intra(const _Float16* __restrict__ qkv,
                                                  const float* __restrict__ ct,
                                                  const float* __restrict__ st,
                                                  float* __restrict__ o) {
    __shared__ float q_s[1024], k_s[1024], v_s[1024], p_s[256];
    int t = blockIdx.x, tid = threadIdx.x;
    int n = t & (SEQ - 1);
    int j0 = (tid & 15) * 2;
    const half4v* src = (const half4v*)(qkv + (size_t)t * 3072);
    ((float4*)q_s)[tid] = rope4(h4f(src[tid]), ct, st, n, j0);
    ((float4*)k_s)[tid] = rope4(h4f(src[256 + tid]), ct, st, n, j0);
    ((float4*)v_s)[tid] = h4f(src[512 + tid]);
    __syncthreads();
    int h = tid >> 4, g = tid & 15;
    const float4* q4 = (const float4*)q_s + h * 16;
    const float4* k4 = (const float4*)k_s + g * 16;
    float accS = 0.f;
#pragma unroll
    for (int i = 0; i < 16; ++i) {
        float4 qa = q4[i], ka = k4[i];
        accS += qa.x * ka.x + qa.y * ka.y + qa.z * ka.z + qa.w * ka.w;
    }
    accS *= 0.125f;
    float mx = accS;
#pragma unroll
    for (int o2 = 8; o2 >= 1; o2 >>= 1) mx = fmaxf(mx, __shfl_xor(mx, o2, 16));
    float e = expf(accS - mx);
    float sm = e;
#pragma unroll
    for (int o2 = 8; o2 >= 1; o2 >>= 1) sm += __shfl_xor(sm, o2, 16);
    p_s[tid] = e / sm;
    __syncthreads();
    int dq = tid & 15;
    float4 acc = {0.f, 0.f, 0.f, 0.f};
    const float4* v4 = (const float4*)v_s;
#pragma unroll
    for (int gg = 0; gg < 16; ++gg) {
        float p = p_s[h * 16 + gg];
        float4 vv = v4[gg * 16 + dq];
        acc.x += p * vv.x; acc.y += p * vv.y; acc.z += p * vv.z; acc.w += p * vv.w;
    }
    ((float4*)(o + (size_t)t * DIMC))[h * 16 + dq] = acc;
}

// ---------------- per-chunk outer product U = k^T v (f16 qkv in, rope fused on k) ----------------
__global__ __launch_bounds__(256) void u_k(const _Float16* __restrict__ qkv,
                                           const float* __restrict__ ct,
                                           const float* __restrict__ st,
                                           float* __restrict__ U) {
    __shared__ float ks_[8192], vs_[8192];
    int bid = blockIdx.x, tid = threadIdx.x;
    int c = bid >> 5, b = (bid >> 4) & 1, h = bid & 15;
    size_t tok = (size_t)(b * SEQ + c * CHUNKL);
#pragma unroll
    for (int j = 0; j < 8; ++j) {
        int idx = j * 256 + tid;
        int l = idx >> 4, c4 = idx & 15;
        int n = (int)((tok + l) & (SEQ - 1));
        const _Float16* kp = qkv + (tok + l) * 3072 + 1024 + h * 64 + c4 * 4;
        const _Float16* vp = qkv + (tok + l) * 3072 + 2048 + h * 64 + c4 * 4;
        ((float4*)ks_)[idx] = rope4(h4f(*(const half4v*)kp), ct, st, n, c4 * 2);
        ((float4*)vs_)[idx] = h4f(*(const half4v*)vp);
    }
    __syncthreads();
    int d = tid >> 2, eg = tid & 3;
    float4 acc[4] = {};
    for (int l = 0; l < CHUNKL; ++l) {
        float kd = ks_[l * 64 + d];
        const float4* vrow = (const float4*)(vs_ + l * 64) + eg * 4;
#pragma unroll
        for (int i = 0; i < 4; ++i) {
            float4 vv = vrow[i];
            acc[i].x += kd * vv.x; acc[i].y += kd * vv.y;
            acc[i].z += kd * vv.z; acc[i].w += kd * vv.w;
        }
    }
    float4* Up = (float4*)(U + (size_t)bid * 4096) + d * 16 + eg * 4;
#pragma unroll
    for (int i = 0; i < 4; ++i) Up[i] = acc[i];
}

// ---------------- diagonal-decay scan over chunks ----------------
__global__ __launch_bounds__(256) void scan_k(const float* __restrict__ U,
                                              const float* __restrict__ dec,
                                              float* __restrict__ kvprev) {
    int t = blockIdx.x * 256 + threadIdx.x;   // 131072
    int b = t >> 16;
    int h = (t >> 12) & 15;
    int d = (t >> 6) & 63;
    float val = 0.f;
#pragma unroll 1
    for (int c = 0; c < NCHUNK; ++c) {
        kvprev[(size_t)c * 131072 + t] = val;
        val = val * dec[(c * 2 + b) * 1024 + h * 64 + d] + U[(size_t)c * 131072 + t];
    }
}

// ---------------- out += q @ kv_prev (f16 qkv in, rope fused on q) ----------------
__global__ __launch_bounds__(256) void out2_k(const _Float16* __restrict__ qkv,
                                              const float* __restrict__ ct,
                                              const float* __restrict__ st,
                                              const float* __restrict__ kvprev,
                                              float* __restrict__ o) {
    __shared__ float kv_s[4096];
    __shared__ float q_s[128 * 65];
    int bid = blockIdx.x, tid = threadIdx.x;
    int c = bid >> 5, b = (bid >> 4) & 1, h = bid & 15;
    size_t tok = (size_t)(b * SEQ + c * CHUNKL);
    const float4* kvsrc = (const float4*)(kvprev + (size_t)c * 131072 + b * 65536 + h * 4096);
#pragma unroll
    for (int j = 0; j < 4; ++j) ((float4*)kv_s)[j * 256 + tid] = kvsrc[j * 256 + tid];
#pragma unroll
    for (int j = 0; j < 8; ++j) {
        int idx = j * 256 + tid;
        int l = idx >> 4, c4 = idx & 15;
        int n = (int)((tok + l) & (SEQ - 1));
        float4 qv = rope4(h4f(*(const half4v*)(qkv + (tok + l) * 3072 + h * 64 + c4 * 4)),
                          ct, st, n, c4 * 2);
        float* dq = q_s + l * 65 + c4 * 4;
        dq[0] = qv.x; dq[1] = qv.y; dq[2] = qv.z; dq[3] = qv.w;
    }
    __syncthreads();
    int l = tid >> 1, eh = tid & 1;
    float4 acc[8] = {};
    const float* qrow = q_s + l * 65;
    for (int d = 0; d < 64; ++d) {
        float qd = qrow[d];
        const float4* kvr = (const float4*)(kv_s + d * 64) + eh * 8;
#pragma unroll
        for (int i = 0; i < 8; ++i) {
            float4 kk = kvr[i];
            acc[i].x += qd * kk.x; acc[i].y += qd * kk.y;
            acc[i].z += qd * kk.z; acc[i].w += qd * kk.w;
        }
    }
    float4* op = (float4*)(o + (tok + l) * DIMC + h * 64 + eh * 32);
#pragma unroll
    for (int i = 0; i < 8; ++i) {
        float4 cur = op[i];
        cur.x += acc[i].x; cur.y += acc[i].y; cur.z += acc[i].z; cur.w += acc[i].w;
        op[i] = cur;
    }
}

// =====================================================================
extern "C" void kernel_launch(void* const* d_in, const int* in_sizes, int n_in,
                              void* d_out, int out_size, void* d_ws, size_t ws_size,
                              hipStream_t stream) {
    const float* x_in       = (const float*)d_in[0];
    const float* norm1_w    = (const float*)d_in[1];
    const float* qkv_w      = (const float*)d_in[2];
    const float* qkv_b      = (const float*)d_in[3];
    const float* gate_w     = (const float*)d_in[4];
    const float* gate_b     = (const float*)d_in[5];
    const float* proj_w     = (const float*)d_in[6];
    const float* proj_b     = (const float*)d_in[7];
    const float* attn_norm_w= (const float*)d_in[8];
    const float* norm2_w    = (const float*)d_in[9];
    const float* fc1_w      = (const float*)d_in[10];
    const float* fc1_b      = (const float*)d_in[11];
    const float* fc2_w      = (const float*)d_in[12];
    const float* fc2_b      = (const float*)d_in[13];
    float* x = (float*)d_out;

    char* wsb = (char*)d_ws;
    size_t off = 0;
    auto carve = [&](size_t bytes) { char* p = wsb + off; off = (off + bytes + 255) & ~(size_t)255; return p; };
    int8_t* q_qkv  = (int8_t*)carve(12582912);
    int8_t* q_gate = (int8_t*)carve(4194304);
    int8_t* q_proj = (int8_t*)carve(4194304);
    int8_t* q_fc1  = (int8_t*)carve(33554432);
    int8_t* q_fc2  = (int8_t*)carve(16777216);
    float*  wsc    = (float*)carve(256);
    float*  part   = (float*)carve(4096);
    float*  ropec  = (float*)carve(524288);
    float*  ropes  = (float*)carve(524288);
    int8_t* qbuf   = (int8_t*)carve(33554432);
    float*  xsbuf  = (float*)carve(32768);
    _Float16* big  = (_Float16*)carve(67108864);  // qkv f16 (50MB) / fc1-mid f16 (67MB)
    float*  attn_o = (float*)carve(33554432);
    float*  Ub     = (float*)carve(16777216);
    float*  kvprev = (float*)carve(16777216);
    float*  decayb = (float*)carve(262144);
    (void)ws_size; (void)in_sizes; (void)n_in; (void)out_size;

    hipMemcpyAsync(x, x_in, (size_t)NTOK * DIMC * sizeof(float), hipMemcpyDeviceToDevice, stream);
    ropetab_k<<<512, 256, 0, stream>>>(ropec, ropes);

    struct WSpec { const float* w; int8_t* q; int perlayer; int arr; };
    WSpec specs[5] = {
        {qkv_w,  q_qkv,  3 * DIMC * DIMC, 0},
        {gate_w, q_gate, DIMC * DIMC,     1},
        {proj_w, q_proj, DIMC * DIMC,     2},
        {fc1_w,  q_fc1,  8192 * 1024,     3},
        {fc2_w,  q_fc2,  DIMC * HIDF,     4},
    };
    for (int a = 0; a < 5; ++a) {
        prep_k<<<dim3(256, NLAYERS), 256, 0, stream>>>(specs[a].w, specs[a].q, part, specs[a].perlayer / 4);
        amean_fin<<<NLAYERS, 256, 0, stream>>>(part, wsc + specs[a].arr * 4, specs[a].perlayer);
    }

    for (int l = 0; l < NLAYERS; ++l) {
        // ---- attention ----
        rmsq_k<<<NTOK, 256, 0, stream>>>(x, norm1_w + l * DIMC, qbuf, xsbuf);
        gemm_i8<EPI_PLANH><<<dim3(64, 24), 256, 0, stream>>>(
            qbuf, q_qkv + (size_t)l * 3145728, xsbuf, wsc + 0 * 4 + l,
            qkv_b + l * 3072, (float*)big, 3072, 1024, 3072);
        gate_decay<<<dim3(64, 8), 256, 0, stream>>>(
            qbuf, q_gate + (size_t)l * 1048576, xsbuf, wsc + 1 * 4 + l,
            gate_b + l * DIMC, decayb);
        attn_intra<<<NTOK, 256, 0, stream>>>(big, ropec, ropes, attn_o);
        u_k<<<1024, 256, 0, stream>>>(big, ropec, ropes, Ub);
        scan_k<<<512, 256, 0, stream>>>(Ub, decayb, kvprev);
        out2_k<<<1024, 256, 0, stream>>>(big, ropec, ropes, kvprev, attn_o);
        rmsq_k<<<NTOK, 256, 0, stream>>>(attn_o, attn_norm_w + l * DIMC, qbuf, xsbuf);
        gemm_i8<EPI_RESID><<<dim3(64, 8), 256, 0, stream>>>(
            qbuf, q_proj + (size_t)l * 1048576, xsbuf, wsc + 2 * 4 + l,
            proj_b + l * DIMC, x, 1024, 1024, 1024);
        // ---- mlp ----
        rmsq_k<<<NTOK, 256, 0, stream>>>(x, norm2_w + l * DIMC, qbuf, xsbuf);
        gemm_fc1<<<dim3(64, 64), 256, 0, stream>>>(
            qbuf, q_fc1 + (size_t)l * 8388608, q_fc1 + (size_t)l * 8388608 + 4194304,
            xsbuf, wsc + 3 * 4 + l, fc1_b + l * 8192, big);
        qrow_k<<<NTOK, 256, 0, stream>>>(big, qbuf, xsbuf);
        gemm_i8<EPI_RESID><<<dim3(64, 8), 256, 0, stream>>>(
            qbuf, q_fc2 + (size_t)l * 4194304, xsbuf, wsc + 4 * 4 + l,
            fc2_b + l * DIMC, x, 1024, 4096, 1024);
    }
}

// Round 12
// 1839.360 us; speedup vs baseline: 1.1666x; 1.0187x over previous
//
#include <hip/hip_runtime.h>
#include <hip/hip_bf16.h>
#include <cstdint>
#include <cstddef>

#define NLAYERS 4
#define SEQ     4096
#define DIMC    1024
#define CHUNKL  128
#define NCHUNK  32
#define HIDF    4096
#define NTOK    8192

using i32x4 = __attribute__((ext_vector_type(4))) int;
typedef _Float16 half4v __attribute__((ext_vector_type(4)));
typedef _Float16 half8v __attribute__((ext_vector_type(8)));

__device__ __forceinline__ float4 h4f(half4v h) {
    float4 r; r.x = (float)h[0]; r.y = (float)h[1]; r.z = (float)h[2]; r.w = (float)h[3];
    return r;
}

__device__ __forceinline__ void gload16(const void* g, void* l) {
    __builtin_amdgcn_global_load_lds((const __attribute__((address_space(1))) void*)g,
                                     (__attribute__((address_space(3))) void*)l, 16, 0, 0);
}

__device__ __forceinline__ float waveSum(float v) {
#pragma unroll
    for (int o = 32; o >= 1; o >>= 1) v += __shfl_down(v, o);
    return v;
}
__device__ __forceinline__ float waveMax(float v) {
#pragma unroll
    for (int o = 32; o >= 1; o >>= 1) v = fmaxf(v, __shfl_down(v, o));
    return v;
}

// ---------------- weight prep: |w| partial sums + sign quant in ONE pass ----------------
__global__ __launch_bounds__(256) void prep_k(const float* __restrict__ w, int8_t* __restrict__ q,
                                              float* __restrict__ part, int perlayer4) {
    __shared__ float red[4];
    int blk = blockIdx.x, layer = blockIdx.y, tid = threadIdx.x;
    const float4* p = (const float4*)(w + (size_t)layer * perlayer4 * 4);
    char4* qp = (char4*)(q + (size_t)layer * perlayer4 * 4);
    float s = 0.f;
    for (int i = blk * 256 + tid; i < perlayer4; i += 256 * 256) {
        float4 v = p[i];
        s += fabsf(v.x) + fabsf(v.y) + fabsf(v.z) + fabsf(v.w);
        char4 o;
        o.x = (v.x > 0.f) ? 1 : ((v.x < 0.f) ? -1 : 0);
        o.y = (v.y > 0.f) ? 1 : ((v.y < 0.f) ? -1 : 0);
        o.z = (v.z > 0.f) ? 1 : ((v.z < 0.f) ? -1 : 0);
        o.w = (v.w > 0.f) ? 1 : ((v.w < 0.f) ? -1 : 0);
        qp[i] = o;
    }
    s = waveSum(s);
    int lane = tid & 63, wv = tid >> 6;
    if (lane == 0) red[wv] = s;
    __syncthreads();
    if (tid == 0) part[layer * 256 + blk] = red[0] + red[1] + red[2] + red[3];
}

__global__ __launch_bounds__(256) void amean_fin(const float* __restrict__ part,
                                                 float* __restrict__ wsc, int perlayer) {
    __shared__ float red[4];
    int layer = blockIdx.x, tid = threadIdx.x;
    float s = part[layer * 256 + tid];
    s = waveSum(s);
    int lane = tid & 63, wv = tid >> 6;
    if (lane == 0) red[wv] = s;
    __syncthreads();
    if (tid == 0) {
        float tot = red[0] + red[1] + red[2] + red[3];
        wsc[layer] = fmaxf(tot / (float)perlayer, 1e-5f);
    }
}

// ---------------- rope tables ----------------
__global__ __launch_bounds__(256) void ropetab_k(float* __restrict__ ct, float* __restrict__ st) {
    int i = blockIdx.x * 256 + threadIdx.x;   // SEQ*32
    int n = i >> 5, j = i & 31;
    float inv = exp2f(-(float)j * (13.287712379549449f / 32.0f)); // 10000^(-j/32)
    float f = (float)n * inv;
    ct[i] = cosf(f);
    st[i] = sinf(f);
}

// rotate a float4 (two rope pairs)
__device__ __forceinline__ float4 rope4(float4 v, const float* ct, const float* st, int n, int j0) {
    float c0 = ct[n * 32 + j0], s0 = st[n * 32 + j0];
    float c1 = ct[n * 32 + j0 + 1], s1 = st[n * 32 + j0 + 1];
    float4 r;
    r.x = v.x * c0 - v.y * s0;
    r.y = v.x * s0 + v.y * c0;
    r.z = v.z * c1 - v.w * s1;
    r.w = v.z * s1 + v.w * c1;
    return r;
}

// ---------------- rmsnorm + row quant (K=1024, f32 input) ----------------
__global__ __launch_bounds__(256) void rmsq_k(const float* __restrict__ x, const float* __restrict__ w,
                                              int8_t* __restrict__ xq, float* __restrict__ xs) {
    __shared__ float red[4];
    int row = blockIdx.x, tid = threadIdx.x;
    const float4* xr = (const float4*)(x + (size_t)row * DIMC);
    float4 v = xr[tid];
    float ss = v.x * v.x + v.y * v.y + v.z * v.z + v.w * v.w;
    ss = waveSum(ss);
    int lane = tid & 63, wv = tid >> 6;
    if (lane == 0) red[wv] = ss;
    __syncthreads();
    float tot = red[0] + red[1] + red[2] + red[3];
    __syncthreads();
    float rinv = 1.0f / sqrtf(tot * (1.0f / (float)DIMC) + 1e-6f);
    float4 wv4 = ((const float4*)w)[tid];
    float4 y;
    y.x = v.x * rinv * wv4.x; y.y = v.y * rinv * wv4.y;
    y.z = v.z * rinv * wv4.z; y.w = v.w * rinv * wv4.w;
    float mx = fmaxf(fmaxf(fabsf(y.x), fabsf(y.y)), fmaxf(fabsf(y.z), fabsf(y.w)));
    mx = waveMax(mx);
    if (lane == 0) red[wv] = mx;
    __syncthreads();
    float s = fmaxf(fmaxf(fmaxf(red[0], red[1]), fmaxf(red[2], red[3])), 1e-5f);
    if (tid == 0) xs[row] = s;
    float qf = 127.0f / s;
    char4 o;
    o.x = (signed char)(int)rintf(y.x * qf);
    o.y = (signed char)(int)rintf(y.y * qf);
    o.z = (signed char)(int)rintf(y.z * qf);
    o.w = (signed char)(int)rintf(y.w * qf);
    ((char4*)xq)[(size_t)row * 256 + tid] = o;
}

// ---------------- row quant only (K=4096, f16 input) ----------------
__global__ __launch_bounds__(256) void qrow_k(const _Float16* __restrict__ in,
                                              int8_t* __restrict__ q, float* __restrict__ xs) {
    __shared__ float red[4];
    int row = blockIdx.x, tid = threadIdx.x;
    const half4v* xr = (const half4v*)(in + (size_t)row * HIDF);
    float4 vv[4];
    float mx = 0.f;
#pragma unroll
    for (int j = 0; j < 4; ++j) {
        vv[j] = h4f(xr[j * 256 + tid]);
        mx = fmaxf(mx, fmaxf(fmaxf(fabsf(vv[j].x), fabsf(vv[j].y)), fmaxf(fabsf(vv[j].z), fabsf(vv[j].w))));
    }
    mx = waveMax(mx);
    int lane = tid & 63, wv = tid >> 6;
    if (lane == 0) red[wv] = mx;
    __syncthreads();
    float s = fmaxf(fmaxf(fmaxf(red[0], red[1]), fmaxf(red[2], red[3])), 1e-5f);
    if (tid == 0) xs[row] = s;
    float qf = 127.0f / s;
#pragma unroll
    for (int j = 0; j < 4; ++j) {
        char4 o;
        o.x = (signed char)(int)rintf(vv[j].x * qf);
        o.y = (signed char)(int)rintf(vv[j].y * qf);
        o.z = (signed char)(int)rintf(vv[j].z * qf);
        o.w = (signed char)(int)rintf(vv[j].w * qf);
        ((char4*)q)[(size_t)row * 1024 + j * 256 + tid] = o;
    }
}

// ==================== int8 MFMA GEMM, 128x128 tile, BK=128, R8-proven core ====================
// EPI_PLANH: f16 output staged through LDS (reuses As/Bs) for full-line coalesced stores
// (R11 lesson: direct 32B f16 chunks cause L2 partial-line RMW -> +50MB FETCH/WRITE).
#define EPI_PLANH 1
#define EPI_RESID 2

template <int EPI>
__global__ __launch_bounds__(256, 4) void gemm_i8(const int8_t* __restrict__ A,
                                                  const int8_t* __restrict__ B,
                                                  const float* __restrict__ xs,
                                                  const float* __restrict__ wsp,
                                                  const float* __restrict__ bias,
                                                  float* __restrict__ out,
                                                  int N, int K, int ldo) {
    __shared__ __align__(16) int8_t smem[32768];
    int8_t* As = smem;
    int8_t* Bs = smem + 16384;
    const int tid = threadIdx.x;
    const int lane = tid & 63, wave = tid >> 6;
    const int wr = wave >> 1, wc = wave & 1;
    const int bm = blockIdx.x, bn = blockIdx.y;

    const int rA = tid >> 3;
    const int colb = (((tid & 7) ^ (rA & 7)) << 4);
    const int8_t* ap = A + (size_t)(bm * 128 + rA) * K + colb;
    const int8_t* bp = B + (size_t)(bn * 128 + rA) * K + colb;
    const size_t rstep = (size_t)32 * K;

    i32x4 acc[4][4] = {};
    const int fr = lane & 15, ks = lane >> 4;

    for (int kt = 0; kt < K; kt += 128) {
#pragma unroll
        for (int p = 0; p < 4; ++p) {
            gload16(ap + kt + (size_t)p * rstep, As + p * 4096 + tid * 16);
            gload16(bp + kt + (size_t)p * rstep, Bs + p * 4096 + tid * 16);
        }
        __syncthreads();
#pragma unroll
        for (int kh = 0; kh < 2; ++kh) {
            i32x4 af[4], bf[4];
#pragma unroll
            for (int m = 0; m < 4; ++m) {
                int ra = wr * 64 + m * 16 + fr;
                af[m] = *(const i32x4*)(As + ra * 128 + (((kh * 4 + ks) ^ (ra & 7)) << 4));
            }
#pragma unroll
            for (int n = 0; n < 4; ++n) {
                int rb = wc * 64 + n * 16 + fr;
                bf[n] = *(const i32x4*)(Bs + rb * 128 + (((kh * 4 + ks) ^ (rb & 7)) << 4));
            }
#pragma unroll
            for (int m = 0; m < 4; ++m)
#pragma unroll
                for (int n = 0; n < 4; ++n)
                    acc[m][n] = __builtin_amdgcn_mfma_i32_16x16x64_i8(af[m], bf[n], acc[m][n], 0, 0, 0);
        }
        __syncthreads();
    }

    const float ws = *wsp;
    if (EPI == EPI_PLANH) {
        // stage f16 tile (128x128 = 32KB) in smem, then linear full-line stores
        _Float16* lds_h = (_Float16*)smem;
#pragma unroll
        for (int m = 0; m < 4; ++m) {
            int rl0 = wr * 64 + m * 16 + ks * 4;
#pragma unroll
            for (int n = 0; n < 4; ++n) {
                int cl = wc * 64 + n * 16 + fr;
                float bv = bias[bn * 128 + cl];
#pragma unroll
                for (int j = 0; j < 4; ++j) {
                    int rl = rl0 + j;
                    float v = (float)acc[m][n][j] * (xs[bm * 128 + rl] * ws * (1.0f / 127.0f)) + bv;
                    lds_h[rl * 128 + cl] = (_Float16)v;
                }
            }
        }
        __syncthreads();
        _Float16* oh = (_Float16*)out;
#pragma unroll
        for (int pass = 0; pass < 8; ++pass) {
            int o = pass * 4096 + tid * 16;       // byte offset in 32KB tile
            int r = o >> 8;                        // 256B per row
            int ce = (o & 255) >> 1;               // f16 elem within row
            *(half8v*)(oh + (size_t)(bm * 128 + r) * ldo + bn * 128 + ce) =
                *(const half8v*)(smem + o);
        }
    } else {
#pragma unroll
        for (int m = 0; m < 4; ++m) {
            int row0 = bm * 128 + wr * 64 + m * 16 + ks * 4;
#pragma unroll
            for (int n = 0; n < 4; ++n) {
                int col = bn * 128 + wc * 64 + n * 16 + fr;
                float bv = bias[col];
#pragma unroll
                for (int j = 0; j < 4; ++j) {
                    int row = row0 + j;
                    float v = (float)acc[m][n][j] * (xs[row] * ws * (1.0f / 127.0f)) + bv;
                    out[(size_t)row * ldo + col] += v;   // EPI_RESID (f32)
                }
            }
        }
    }
    (void)N;
}

// ---------------- gate GEMM + sigmoid + chunk-mean fused (R8-proven core) ----------------
__global__ __launch_bounds__(256, 4) void gate_decay(const int8_t* __restrict__ A,
                                                     const int8_t* __restrict__ B,
                                                     const float* __restrict__ xs,
                                                     const float* __restrict__ wsp,
                                                     const float* __restrict__ bias,
                                                     float* __restrict__ dec) {
    __shared__ __align__(16) int8_t As[16384];
    __shared__ __align__(16) int8_t Bs[16384];
    __shared__ float dsum[2][128];
    const int tid = threadIdx.x;
    const int lane = tid & 63, wave = tid >> 6;
    const int wr = wave >> 1, wc = wave & 1;
    const int bm = blockIdx.x, bn = blockIdx.y;
    const int K = 1024;

    const int rA = tid >> 3;
    const int colb = (((tid & 7) ^ (rA & 7)) << 4);
    const int8_t* ap = A + (size_t)(bm * 128 + rA) * K + colb;
    const int8_t* bp = B + (size_t)(bn * 128 + rA) * K + colb;
    const size_t rstep = (size_t)32 * K;

    i32x4 acc[4][4] = {};
    const int fr = lane & 15, ks = lane >> 4;

    for (int kt = 0; kt < K; kt += 128) {
#pragma unroll
        for (int p = 0; p < 4; ++p) {
            gload16(ap + kt + (size_t)p * rstep, As + p * 4096 + tid * 16);
            gload16(bp + kt + (size_t)p * rstep, Bs + p * 4096 + tid * 16);
        }
        __syncthreads();
#pragma unroll
        for (int kh = 0; kh < 2; ++kh) {
            i32x4 af[4], bf[4];
#pragma unroll
            for (int m = 0; m < 4; ++m) {
                int ra = wr * 64 + m * 16 + fr;
                af[m] = *(const i32x4*)(As + ra * 128 + (((kh * 4 + ks) ^ (ra & 7)) << 4));
            }
#pragma unroll
            for (int n = 0; n < 4; ++n) {
                int rb = wc * 64 + n * 16 + fr;
                bf[n] = *(const i32x4*)(Bs + rb * 128 + (((kh * 4 + ks) ^ (rb & 7)) << 4));
            }
#pragma unroll
            for (int m = 0; m < 4; ++m)
#pragma unroll
                for (int n = 0; n < 4; ++n)
                    acc[m][n] = __builtin_amdgcn_mfma_i32_16x16x64_i8(af[m], bf[n], acc[m][n], 0, 0, 0);
        }
        __syncthreads();
    }

    const float ws = *wsp;
#pragma unroll
    for (int n = 0; n < 4; ++n) {
        int col = bn * 128 + wc * 64 + n * 16 + fr;
        float bv = bias[col];
        float sn = 0.f;
#pragma unroll
        for (int m = 0; m < 4; ++m) {
            int row0 = bm * 128 + wr * 64 + m * 16 + ks * 4;
#pragma unroll
            for (int j = 0; j < 4; ++j) {
                int row = row0 + j;
                float v = (float)acc[m][n][j] * (xs[row] * ws * (1.0f / 127.0f)) + bv;
                sn += 1.0f / (1.0f + expf(-v));
            }
        }
        sn += __shfl_down(sn, 32);
        sn += __shfl_down(sn, 16);
        if (lane < 16) dsum[wr][wc * 64 + n * 16 + lane] = sn;
    }
    __syncthreads();
    if (tid < 128) {
        int b = bm >> 5, c = bm & 31;
        dec[(size_t)(c * 2 + b) * 1024 + bn * 128 + tid] =
            (dsum[0][tid] + dsum[1][tid]) * (1.0f / 128.0f);
    }
}

// ---------------- fc1 fused dual-B GEMM + SwiGLU, 128x64 tile, BK=128, staged f16 out ------
__global__ __launch_bounds__(256, 4) void gemm_fc1(const int8_t* __restrict__ A,
                                                   const int8_t* __restrict__ B1,
                                                   const int8_t* __restrict__ B2,
                                                   const float* __restrict__ xs,
                                                   const float* __restrict__ wsp,
                                                   const float* __restrict__ bias,
                                                   _Float16* __restrict__ out) {
    __shared__ __align__(16) int8_t smem[32768];
    int8_t* As  = smem;
    int8_t* Bs1 = smem + 16384;
    int8_t* Bs2 = smem + 24576;
    const int tid = threadIdx.x;
    const int lane = tid & 63, wave = tid >> 6;
    const int wr = wave >> 1, wc = wave & 1;   // 2x2 waves over (128 rows, 64 cols)
    const int bm = blockIdx.x, bn = blockIdx.y;
    const int K = 1024;

    const int rA = tid >> 3;                         // [0,32)
    const int colb = (((tid & 7) ^ (rA & 7)) << 4);
    const int8_t* ap  = A  + (size_t)(bm * 128 + rA) * K + colb;
    const int8_t* b1p = B1 + (size_t)(bn * 64 + rA) * K + colb;
    const int8_t* b2p = B2 + (size_t)(bn * 64 + rA) * K + colb;
    const size_t rstep = (size_t)32 * K;

    i32x4 acc1[4][2] = {}, acc2[4][2] = {};
    const int fr = lane & 15, ks = lane >> 4;

    for (int kt = 0; kt < K; kt += 128) {
#pragma unroll
        for (int p = 0; p < 4; ++p)
            gload16(ap + kt + (size_t)p * rstep, As + p * 4096 + tid * 16);
#pragma unroll
        for (int p = 0; p < 2; ++p) {
            gload16(b1p + kt + (size_t)p * rstep, Bs1 + p * 4096 + tid * 16);
            gload16(b2p + kt + (size_t)p * rstep, Bs2 + p * 4096 + tid * 16);
        }
        __syncthreads();
#pragma unroll
        for (int kh = 0; kh < 2; ++kh) {
            i32x4 af[4], b1f[2], b2f[2];
#pragma unroll
            for (int m = 0; m < 4; ++m) {
                int ra = wr * 64 + m * 16 + fr;
                af[m] = *(const i32x4*)(As + ra * 128 + (((kh * 4 + ks) ^ (ra & 7)) << 4));
            }
#pragma unroll
            for (int n = 0; n < 2; ++n) {
                int rb = wc * 32 + n * 16 + fr;      // [0,64)
                int off = rb * 128 + (((kh * 4 + ks) ^ (rb & 7)) << 4);
                b1f[n] = *(const i32x4*)(Bs1 + off);
                b2f[n] = *(const i32x4*)(Bs2 + off);
            }
#pragma unroll
            for (int m = 0; m < 4; ++m)
#pragma unroll
                for (int n = 0; n < 2; ++n) {
                    acc1[m][n] = __builtin_amdgcn_mfma_i32_16x16x64_i8(af[m], b1f[n], acc1[m][n], 0, 0, 0);
                    acc2[m][n] = __builtin_amdgcn_mfma_i32_16x16x64_i8(af[m], b2f[n], acc2[m][n], 0, 0, 0);
                }
        }
        __syncthreads();
    }

    const float ws = *wsp;
    // stage f16 tile (128x64 = 16KB) in smem, then linear full-line stores
    _Float16* lds_h = (_Float16*)smem;
#pragma unroll
    for (int m = 0; m < 4; ++m) {
        int rl0 = wr * 64 + m * 16 + ks * 4;
#pragma unroll
        for (int n = 0; n < 2; ++n) {
            int cl = wc * 32 + n * 16 + fr;
            float ba = bias[bn * 64 + cl];
            float bg = bias[bn * 64 + cl + 4096];
#pragma unroll
            for (int j = 0; j < 4; ++j) {
                int rl = rl0 + j;
                float sc = xs[bm * 128 + rl] * ws * (1.0f / 127.0f);
                float a = (float)acc1[m][n][j] * sc + ba;
                float g = (float)acc2[m][n][j] * sc + bg;
                lds_h[rl * 64 + cl] = (_Float16)(a * g / (1.0f + expf(-g)));
            }
        }
    }
    __syncthreads();
#pragma unroll
    for (int pass = 0; pass < 4; ++pass) {
        int o = pass * 4096 + tid * 16;       // byte offset in 16KB tile
        int r = o >> 7;                        // 128B per row
        int ce = (o & 127) >> 1;               // f16 elem within row
        *(half8v*)(out + (size_t)(bm * 128 + r) * HIDF + bn * 64 + ce) =
            *(const half8v*)(smem + o);
    }
}

// ---------------- per-token head-mix softmax attention (f16 qkv in, rope fused) ----------------
__global__ __launch_bounds__(256) void attn_intra(const _Float16* __restrict__ qkv,
                                                  const float* __restrict__ ct,
                                                  const float* __restrict__ st,
                                                  float* __restrict__ o) {
    __shared__ float q_s[1024], k_s[1024], v_s[1024], p_s[256];
    int t = blockIdx.x, tid = threadIdx.x;
    int n = t & (SEQ - 1);
    int j0 = (tid & 15) * 2;
    const half4v* src = (const half4v*)(qkv + (size_t)t * 3072);
    ((float4*)q_s)[tid] = rope4(h4f(src[tid]), ct, st, n, j0);
    ((float4*)k_s)[tid] = rope4(h4f(src[256 + tid]), ct, st, n, j0);
    ((float4*)v_s)[tid] = h4f(src[512 + tid]);
    __syncthreads();
    int h = tid >> 4, g = tid & 15;
    const float4* q4 = (const float4*)q_s + h * 16;
    const float4* k4 = (const float4*)k_s + g * 16;
    float accS = 0.f;
#pragma unroll
    for (int i = 0; i < 16; ++i) {
        float4 qa = q4[i], ka = k4[i];
        accS += qa.x * ka.x + qa.y * ka.y + qa.z * ka.z + qa.w * ka.w;
    }
    accS *= 0.125f;
    float mx = accS;
#pragma unroll
    for (int o2 = 8; o2 >= 1; o2 >>= 1) mx = fmaxf(mx, __shfl_xor(mx, o2, 16));
    float e = expf(accS - mx);
    float sm = e;
#pragma unroll
    for (int o2 = 8; o2 >= 1; o2 >>= 1) sm += __shfl_xor(sm, o2, 16);
    p_s[tid] = e / sm;
    __syncthreads();
    int dq = tid & 15;
    float4 acc = {0.f, 0.f, 0.f, 0.f};
    const float4* v4 = (const float4*)v_s;
#pragma unroll
    for (int gg = 0; gg < 16; ++gg) {
        float p = p_s[h * 16 + gg];
        float4 vv = v4[gg * 16 + dq];
        acc.x += p * vv.x; acc.y += p * vv.y; acc.z += p * vv.z; acc.w += p * vv.w;
    }
    ((float4*)(o + (size_t)t * DIMC))[h * 16 + dq] = acc;
}

// ---------------- per-chunk outer product U = k^T v (f16 qkv in, rope fused on k) ----------------
__global__ __launch_bounds__(256) void u_k(const _Float16* __restrict__ qkv,
                                           const float* __restrict__ ct,
                                           const float* __restrict__ st,
                                           float* __restrict__ U) {
    __shared__ float ks_[8192], vs_[8192];
    int bid = blockIdx.x, tid = threadIdx.x;
    int c = bid >> 5, b = (bid >> 4) & 1, h = bid & 15;
    size_t tok = (size_t)(b * SEQ + c * CHUNKL);
#pragma unroll
    for (int j = 0; j < 8; ++j) {
        int idx = j * 256 + tid;
        int l = idx >> 4, c4 = idx & 15;
        int n = (int)((tok + l) & (SEQ - 1));
        const _Float16* kp = qkv + (tok + l) * 3072 + 1024 + h * 64 + c4 * 4;
        const _Float16* vp = qkv + (tok + l) * 3072 + 2048 + h * 64 + c4 * 4;
        ((float4*)ks_)[idx] = rope4(h4f(*(const half4v*)kp), ct, st, n, c4 * 2);
        ((float4*)vs_)[idx] = h4f(*(const half4v*)vp);
    }
    __syncthreads();
    int d = tid >> 2, eg = tid & 3;
    float4 acc[4] = {};
    for (int l = 0; l < CHUNKL; ++l) {
        float kd = ks_[l * 64 + d];
        const float4* vrow = (const float4*)(vs_ + l * 64) + eg * 4;
#pragma unroll
        for (int i = 0; i < 4; ++i) {
            float4 vv = vrow[i];
            acc[i].x += kd * vv.x; acc[i].y += kd * vv.y;
            acc[i].z += kd * vv.z; acc[i].w += kd * vv.w;
        }
    }
    float4* Up = (float4*)(U + (size_t)bid * 4096) + d * 16 + eg * 4;
#pragma unroll
    for (int i = 0; i < 4; ++i) Up[i] = acc[i];
}

// ---------------- diagonal-decay scan over chunks ----------------
__global__ __launch_bounds__(256) void scan_k(const float* __restrict__ U,
                                              const float* __restrict__ dec,
                                              float* __restrict__ kvprev) {
    int t = blockIdx.x * 256 + threadIdx.x;   // 131072
    int b = t >> 16;
    int h = (t >> 12) & 15;
    int d = (t >> 6) & 63;
    float val = 0.f;
#pragma unroll 1
    for (int c = 0; c < NCHUNK; ++c) {
        kvprev[(size_t)c * 131072 + t] = val;
        val = val * dec[(c * 2 + b) * 1024 + h * 64 + d] + U[(size_t)c * 131072 + t];
    }
}

// ---------------- out += q @ kv_prev (f16 qkv in, rope fused on q) ----------------
__global__ __launch_bounds__(256) void out2_k(const _Float16* __restrict__ qkv,
                                              const float* __restrict__ ct,
                                              const float* __restrict__ st,
                                              const float* __restrict__ kvprev,
                                              float* __restrict__ o) {
    __shared__ float kv_s[4096];
    __shared__ float q_s[128 * 65];
    int bid = blockIdx.x, tid = threadIdx.x;
    int c = bid >> 5, b = (bid >> 4) & 1, h = bid & 15;
    size_t tok = (size_t)(b * SEQ + c * CHUNKL);
    const float4* kvsrc = (const float4*)(kvprev + (size_t)c * 131072 + b * 65536 + h * 4096);
#pragma unroll
    for (int j = 0; j < 4; ++j) ((float4*)kv_s)[j * 256 + tid] = kvsrc[j * 256 + tid];
#pragma unroll
    for (int j = 0; j < 8; ++j) {
        int idx = j * 256 + tid;
        int l = idx >> 4, c4 = idx & 15;
        int n = (int)((tok + l) & (SEQ - 1));
        float4 qv = rope4(h4f(*(const half4v*)(qkv + (tok + l) * 3072 + h * 64 + c4 * 4)),
                          ct, st, n, c4 * 2);
        float* dq = q_s + l * 65 + c4 * 4;
        dq[0] = qv.x; dq[1] = qv.y; dq[2] = qv.z; dq[3] = qv.w;
    }
    __syncthreads();
    int l = tid >> 1, eh = tid & 1;
    float4 acc[8] = {};
    const float* qrow = q_s + l * 65;
    for (int d = 0; d < 64; ++d) {
        float qd = qrow[d];
        const float4* kvr = (const float4*)(kv_s + d * 64) + eh * 8;
#pragma unroll
        for (int i = 0; i < 8; ++i) {
            float4 kk = kvr[i];
            acc[i].x += qd * kk.x; acc[i].y += qd * kk.y;
            acc[i].z += qd * kk.z; acc[i].w += qd * kk.w;
        }
    }
    float4* op = (float4*)(o + (tok + l) * DIMC + h * 64 + eh * 32);
#pragma unroll
    for (int i = 0; i < 8; ++i) {
        float4 cur = op[i];
        cur.x += acc[i].x; cur.y += acc[i].y; cur.z += acc[i].z; cur.w += acc[i].w;
        op[i] = cur;
    }
}

// =====================================================================
extern "C" void kernel_launch(void* const* d_in, const int* in_sizes, int n_in,
                              void* d_out, int out_size, void* d_ws, size_t ws_size,
                              hipStream_t stream) {
    const float* x_in       = (const float*)d_in[0];
    const float* norm1_w    = (const float*)d_in[1];
    const float* qkv_w      = (const float*)d_in[2];
    const float* qkv_b      = (const float*)d_in[3];
    const float* gate_w     = (const float*)d_in[4];
    const float* gate_b     = (const float*)d_in[5];
    const float* proj_w     = (const float*)d_in[6];
    const float* proj_b     = (const float*)d_in[7];
    const float* attn_norm_w= (const float*)d_in[8];
    const float* norm2_w    = (const float*)d_in[9];
    const float* fc1_w      = (const float*)d_in[10];
    const float* fc1_b      = (const float*)d_in[11];
    const float* fc2_w      = (const float*)d_in[12];
    const float* fc2_b      = (const float*)d_in[13];
    float* x = (float*)d_out;

    char* wsb = (char*)d_ws;
    size_t off = 0;
    auto carve = [&](size_t bytes) { char* p = wsb + off; off = (off + bytes + 255) & ~(size_t)255; return p; };
    int8_t* q_qkv  = (int8_t*)carve(12582912);
    int8_t* q_gate = (int8_t*)carve(4194304);
    int8_t* q_proj = (int8_t*)carve(4194304);
    int8_t* q_fc1  = (int8_t*)carve(33554432);
    int8_t* q_fc2  = (int8_t*)carve(16777216);
    float*  wsc    = (float*)carve(256);
    float*  part   = (float*)carve(4096);
    float*  ropec  = (float*)carve(524288);
    float*  ropes  = (float*)carve(524288);
    int8_t* qbuf   = (int8_t*)carve(33554432);
    float*  xsbuf  = (float*)carve(32768);
    _Float16* big  = (_Float16*)carve(67108864);  // qkv f16 (50MB) / fc1-mid f16 (67MB)
    float*  attn_o = (float*)carve(33554432);
    float*  Ub     = (float*)carve(16777216);
    float*  kvprev = (float*)carve(16777216);
    float*  decayb = (float*)carve(262144);
    (void)ws_size; (void)in_sizes; (void)n_in; (void)out_size;

    hipMemcpyAsync(x, x_in, (size_t)NTOK * DIMC * sizeof(float), hipMemcpyDeviceToDevice, stream);
    ropetab_k<<<512, 256, 0, stream>>>(ropec, ropes);

    struct WSpec { const float* w; int8_t* q; int perlayer; int arr; };
    WSpec specs[5] = {
        {qkv_w,  q_qkv,  3 * DIMC * DIMC, 0},
        {gate_w, q_gate, DIMC * DIMC,     1},
        {proj_w, q_proj, DIMC * DIMC,     2},
        {fc1_w,  q_fc1,  8192 * 1024,     3},
        {fc2_w,  q_fc2,  DIMC * HIDF,     4},
    };
    for (int a = 0; a < 5; ++a) {
        prep_k<<<dim3(256, NLAYERS), 256, 0, stream>>>(specs[a].w, specs[a].q, part, specs[a].perlayer / 4);
        amean_fin<<<NLAYERS, 256, 0, stream>>>(part, wsc + specs[a].arr * 4, specs[a].perlayer);
    }

    for (int l = 0; l < NLAYERS; ++l) {
        // ---- attention ----
        rmsq_k<<<NTOK, 256, 0, stream>>>(x, norm1_w + l * DIMC, qbuf, xsbuf);
        gemm_i8<EPI_PLANH><<<dim3(64, 24), 256, 0, stream>>>(
            qbuf, q_qkv + (size_t)l * 3145728, xsbuf, wsc + 0 * 4 + l,
            qkv_b + l * 3072, (float*)big, 3072, 1024, 3072);
        gate_decay<<<dim3(64, 8), 256, 0, stream>>>(
            qbuf, q_gate + (size_t)l * 1048576, xsbuf, wsc + 1 * 4 + l,
            gate_b + l * DIMC, decayb);
        attn_intra<<<NTOK, 256, 0, stream>>>(big, ropec, ropes, attn_o);
        u_k<<<1024, 256, 0, stream>>>(big, ropec, ropes, Ub);
        scan_k<<<512, 256, 0, stream>>>(Ub, decayb, kvprev);
        out2_k<<<1024, 256, 0, stream>>>(big, ropec, ropes, kvprev, attn_o);
        rmsq_k<<<NTOK, 256, 0, stream>>>(attn_o, attn_norm_w + l * DIMC, qbuf, xsbuf);
        gemm_i8<EPI_RESID><<<dim3(64, 8), 256, 0, stream>>>(
            qbuf, q_proj + (size_t)l * 1048576, xsbuf, wsc + 2 * 4 + l,
            proj_b + l * DIMC, x, 1024, 1024, 1024);
        // ---- mlp ----
        rmsq_k<<<NTOK, 256, 0, stream>>>(x, norm2_w + l * DIMC, qbuf, xsbuf);
        gemm_fc1<<<dim3(64, 64), 256, 0, stream>>>(
            qbuf, q_fc1 + (size_t)l * 8388608, q_fc1 + (size_t)l * 8388608 + 4194304,
            xsbuf, wsc + 3 * 4 + l, fc1_b + l * 8192, big);
        qrow_k<<<NTOK, 256, 0, stream>>>(big, qbuf, xsbuf);
        gemm_i8<EPI_RESID><<<dim3(64, 8), 256, 0, stream>>>(
            qbuf, q_fc2 + (size_t)l * 4194304, xsbuf, wsc + 4 * 4 + l,
            fc2_b + l * DIMC, x, 1024, 4096, 1024);
    }
}

// Round 13
// 1766.544 us; speedup vs baseline: 1.2147x; 1.0412x over previous
//
#include <hip/hip_runtime.h>
#include <hip/hip_bf16.h>
#include <cstdint>
#include <cstddef>

#define NLAYERS 4
#define SEQ     4096
#define DIMC    1024
#define CHUNKL  128
#define NCHUNK  32
#define HIDF    4096
#define NTOK    8192

using i32x4 = __attribute__((ext_vector_type(4))) int;
typedef _Float16 half4v __attribute__((ext_vector_type(4)));
typedef _Float16 half8v __attribute__((ext_vector_type(8)));

__device__ __forceinline__ float4 h4f(half4v h) {
    float4 r; r.x = (float)h[0]; r.y = (float)h[1]; r.z = (float)h[2]; r.w = (float)h[3];
    return r;
}

__device__ __forceinline__ void gload16(const void* g, void* l) {
    __builtin_amdgcn_global_load_lds((const __attribute__((address_space(1))) void*)g,
                                     (__attribute__((address_space(3))) void*)l, 16, 0, 0);
}

__device__ __forceinline__ float waveSum(float v) {
#pragma unroll
    for (int o = 32; o >= 1; o >>= 1) v += __shfl_down(v, o);
    return v;
}
__device__ __forceinline__ float waveMax(float v) {
#pragma unroll
    for (int o = 32; o >= 1; o >>= 1) v = fmaxf(v, __shfl_down(v, o));
    return v;
}

// ---------------- weight prep: |w| partial sums + sign quant in ONE pass ----------------
__global__ __launch_bounds__(256) void prep_k(const float* __restrict__ w, int8_t* __restrict__ q,
                                              float* __restrict__ part, int perlayer4) {
    __shared__ float red[4];
    int blk = blockIdx.x, layer = blockIdx.y, tid = threadIdx.x;
    const float4* p = (const float4*)(w + (size_t)layer * perlayer4 * 4);
    char4* qp = (char4*)(q + (size_t)layer * perlayer4 * 4);
    float s = 0.f;
    for (int i = blk * 256 + tid; i < perlayer4; i += 256 * 256) {
        float4 v = p[i];
        s += fabsf(v.x) + fabsf(v.y) + fabsf(v.z) + fabsf(v.w);
        char4 o;
        o.x = (v.x > 0.f) ? 1 : ((v.x < 0.f) ? -1 : 0);
        o.y = (v.y > 0.f) ? 1 : ((v.y < 0.f) ? -1 : 0);
        o.z = (v.z > 0.f) ? 1 : ((v.z < 0.f) ? -1 : 0);
        o.w = (v.w > 0.f) ? 1 : ((v.w < 0.f) ? -1 : 0);
        qp[i] = o;
    }
    s = waveSum(s);
    int lane = tid & 63, wv = tid >> 6;
    if (lane == 0) red[wv] = s;
    __syncthreads();
    if (tid == 0) part[layer * 256 + blk] = red[0] + red[1] + red[2] + red[3];
}

__global__ __launch_bounds__(256) void amean_fin(const float* __restrict__ part,
                                                 float* __restrict__ wsc, int perlayer) {
    __shared__ float red[4];
    int layer = blockIdx.x, tid = threadIdx.x;
    float s = part[layer * 256 + tid];
    s = waveSum(s);
    int lane = tid & 63, wv = tid >> 6;
    if (lane == 0) red[wv] = s;
    __syncthreads();
    if (tid == 0) {
        float tot = red[0] + red[1] + red[2] + red[3];
        wsc[layer] = fmaxf(tot / (float)perlayer, 1e-5f);
    }
}

// ---------------- rope tables ----------------
__global__ __launch_bounds__(256) void ropetab_k(float* __restrict__ ct, float* __restrict__ st) {
    int i = blockIdx.x * 256 + threadIdx.x;   // SEQ*32
    int n = i >> 5, j = i & 31;
    float inv = exp2f(-(float)j * (13.287712379549449f / 32.0f)); // 10000^(-j/32)
    float f = (float)n * inv;
    ct[i] = cosf(f);
    st[i] = sinf(f);
}

// rotate a float4 (two rope pairs)
__device__ __forceinline__ float4 rope4(float4 v, const float* ct, const float* st, int n, int j0) {
    float c0 = ct[n * 32 + j0], s0 = st[n * 32 + j0];
    float c1 = ct[n * 32 + j0 + 1], s1 = st[n * 32 + j0 + 1];
    float4 r;
    r.x = v.x * c0 - v.y * s0;
    r.y = v.x * s0 + v.y * c0;
    r.z = v.z * c1 - v.w * s1;
    r.w = v.z * s1 + v.w * c1;
    return r;
}

// ---------------- rmsnorm + row quant (K=1024, f32 input) ----------------
__global__ __launch_bounds__(256) void rmsq_k(const float* __restrict__ x, const float* __restrict__ w,
                                              int8_t* __restrict__ xq, float* __restrict__ xs) {
    __shared__ float red[4];
    int row = blockIdx.x, tid = threadIdx.x;
    const float4* xr = (const float4*)(x + (size_t)row * DIMC);
    float4 v = xr[tid];
    float ss = v.x * v.x + v.y * v.y + v.z * v.z + v.w * v.w;
    ss = waveSum(ss);
    int lane = tid & 63, wv = tid >> 6;
    if (lane == 0) red[wv] = ss;
    __syncthreads();
    float tot = red[0] + red[1] + red[2] + red[3];
    __syncthreads();
    float rinv = 1.0f / sqrtf(tot * (1.0f / (float)DIMC) + 1e-6f);
    float4 wv4 = ((const float4*)w)[tid];
    float4 y;
    y.x = v.x * rinv * wv4.x; y.y = v.y * rinv * wv4.y;
    y.z = v.z * rinv * wv4.z; y.w = v.w * rinv * wv4.w;
    float mx = fmaxf(fmaxf(fabsf(y.x), fabsf(y.y)), fmaxf(fabsf(y.z), fabsf(y.w)));
    mx = waveMax(mx);
    if (lane == 0) red[wv] = mx;
    __syncthreads();
    float s = fmaxf(fmaxf(fmaxf(red[0], red[1]), fmaxf(red[2], red[3])), 1e-5f);
    if (tid == 0) xs[row] = s;
    float qf = 127.0f / s;
    char4 o;
    o.x = (signed char)(int)rintf(y.x * qf);
    o.y = (signed char)(int)rintf(y.y * qf);
    o.z = (signed char)(int)rintf(y.z * qf);
    o.w = (signed char)(int)rintf(y.w * qf);
    ((char4*)xq)[(size_t)row * 256 + tid] = o;
}

// ---------------- row quant only (K=4096, f16 input) ----------------
__global__ __launch_bounds__(256) void qrow_k(const _Float16* __restrict__ in,
                                              int8_t* __restrict__ q, float* __restrict__ xs) {
    __shared__ float red[4];
    int row = blockIdx.x, tid = threadIdx.x;
    const half4v* xr = (const half4v*)(in + (size_t)row * HIDF);
    float4 vv[4];
    float mx = 0.f;
#pragma unroll
    for (int j = 0; j < 4; ++j) {
        vv[j] = h4f(xr[j * 256 + tid]);
        mx = fmaxf(mx, fmaxf(fmaxf(fabsf(vv[j].x), fabsf(vv[j].y)), fmaxf(fabsf(vv[j].z), fabsf(vv[j].w))));
    }
    mx = waveMax(mx);
    int lane = tid & 63, wv = tid >> 6;
    if (lane == 0) red[wv] = mx;
    __syncthreads();
    float s = fmaxf(fmaxf(fmaxf(red[0], red[1]), fmaxf(red[2], red[3])), 1e-5f);
    if (tid == 0) xs[row] = s;
    float qf = 127.0f / s;
#pragma unroll
    for (int j = 0; j < 4; ++j) {
        char4 o;
        o.x = (signed char)(int)rintf(vv[j].x * qf);
        o.y = (signed char)(int)rintf(vv[j].y * qf);
        o.z = (signed char)(int)rintf(vv[j].z * qf);
        o.w = (signed char)(int)rintf(vv[j].w * qf);
        ((char4*)q)[(size_t)row * 1024 + j * 256 + tid] = o;
    }
}

// ==================== merged qkv+gate GEMM, 128x128 tile, BK=128, grid (64,32) ==============
// bn<24: qkv columns -> staged f16 write (ldo 3072). bn>=24: gate columns -> sigmoid+chunk-mean
// decay epilogue (R8-proven gate_decay math). Same MFMA order as before -> bit-identical.
__global__ __launch_bounds__(256, 4) void gemm_qkvg(const int8_t* __restrict__ A,
                                                    const int8_t* __restrict__ Bq,
                                                    const int8_t* __restrict__ Bg,
                                                    const float* __restrict__ xs,
                                                    const float* __restrict__ wsq_p,
                                                    const float* __restrict__ wsg_p,
                                                    const float* __restrict__ bq,
                                                    const float* __restrict__ bg,
                                                    _Float16* __restrict__ outq,
                                                    float* __restrict__ dec) {
    __shared__ __align__(16) int8_t smem[32768];
    __shared__ float dsum[2][128];
    int8_t* As = smem;
    int8_t* Bs = smem + 16384;
    const int tid = threadIdx.x;
    const int lane = tid & 63, wave = tid >> 6;
    const int wr = wave >> 1, wc = wave & 1;
    const int bm = blockIdx.x, bn = blockIdx.y;
    const int K = 1024;
    const bool isGate = bn >= 24;
    const int bcol0 = isGate ? (bn - 24) * 128 : bn * 128;
    const int8_t* Bsel = isGate ? Bg : Bq;

    const int rA = tid >> 3;
    const int colb = (((tid & 7) ^ (rA & 7)) << 4);
    const int8_t* ap = A + (size_t)(bm * 128 + rA) * K + colb;
    const int8_t* bp = Bsel + (size_t)(bcol0 + rA) * K + colb;
    const size_t rstep = (size_t)32 * K;

    i32x4 acc[4][4] = {};
    const int fr = lane & 15, ks = lane >> 4;

    for (int kt = 0; kt < K; kt += 128) {
#pragma unroll
        for (int p = 0; p < 4; ++p) {
            gload16(ap + kt + (size_t)p * rstep, As + p * 4096 + tid * 16);
            gload16(bp + kt + (size_t)p * rstep, Bs + p * 4096 + tid * 16);
        }
        __syncthreads();
#pragma unroll
        for (int kh = 0; kh < 2; ++kh) {
            i32x4 af[4], bf[4];
#pragma unroll
            for (int m = 0; m < 4; ++m) {
                int ra = wr * 64 + m * 16 + fr;
                af[m] = *(const i32x4*)(As + ra * 128 + (((kh * 4 + ks) ^ (ra & 7)) << 4));
            }
#pragma unroll
            for (int n = 0; n < 4; ++n) {
                int rb = wc * 64 + n * 16 + fr;
                bf[n] = *(const i32x4*)(Bs + rb * 128 + (((kh * 4 + ks) ^ (rb & 7)) << 4));
            }
#pragma unroll
            for (int m = 0; m < 4; ++m)
#pragma unroll
                for (int n = 0; n < 4; ++n)
                    acc[m][n] = __builtin_amdgcn_mfma_i32_16x16x64_i8(af[m], bf[n], acc[m][n], 0, 0, 0);
        }
        __syncthreads();
    }

    if (isGate) {
        const float ws = *wsg_p;
#pragma unroll
        for (int n = 0; n < 4; ++n) {
            int cl = wc * 64 + n * 16 + fr;
            float bv = bg[bcol0 + cl];
            float sn = 0.f;
#pragma unroll
            for (int m = 0; m < 4; ++m) {
                int row0 = bm * 128 + wr * 64 + m * 16 + ks * 4;
#pragma unroll
                for (int j = 0; j < 4; ++j) {
                    int row = row0 + j;
                    float v = (float)acc[m][n][j] * (xs[row] * ws * (1.0f / 127.0f)) + bv;
                    sn += 1.0f / (1.0f + expf(-v));
                }
            }
            sn += __shfl_down(sn, 32);
            sn += __shfl_down(sn, 16);
            if (lane < 16) dsum[wr][wc * 64 + n * 16 + lane] = sn;
        }
        __syncthreads();
        if (tid < 128) {
            int b = bm >> 5, c = bm & 31;
            dec[(size_t)(c * 2 + b) * 1024 + bcol0 + tid] =
                (dsum[0][tid] + dsum[1][tid]) * (1.0f / 128.0f);
        }
    } else {
        const float ws = *wsq_p;
        // stage f16 tile (128x128 = 32KB) in smem, then linear full-line stores
        _Float16* lds_h = (_Float16*)smem;
#pragma unroll
        for (int m = 0; m < 4; ++m) {
            int rl0 = wr * 64 + m * 16 + ks * 4;
#pragma unroll
            for (int n = 0; n < 4; ++n) {
                int cl = wc * 64 + n * 16 + fr;
                float bv = bq[bcol0 + cl];
#pragma unroll
                for (int j = 0; j < 4; ++j) {
                    int rl = rl0 + j;
                    float v = (float)acc[m][n][j] * (xs[bm * 128 + rl] * ws * (1.0f / 127.0f)) + bv;
                    lds_h[rl * 128 + cl] = (_Float16)v;
                }
            }
        }
        __syncthreads();
#pragma unroll
        for (int pass = 0; pass < 8; ++pass) {
            int o = pass * 4096 + tid * 16;       // byte offset in 32KB tile
            int r = o >> 8;                        // 256B per row
            int ce = (o & 255) >> 1;               // f16 elem within row
            *(half8v*)(outq + (size_t)(bm * 128 + r) * 3072 + bcol0 + ce) =
                *(const half8v*)(smem + o);
        }
    }
}

// ==================== 128x64-tile int8 GEMM, BK=128, EPI_RESID f32 (fc2 / proj) =============
// fc1-proven geometry minus dual-B: 24KB LDS, acc[4][2] (32 AGPR) -> 4 blocks/CU.
__global__ __launch_bounds__(256, 4) void gemm_n64(const int8_t* __restrict__ A,
                                                   const int8_t* __restrict__ B,
                                                   const float* __restrict__ xs,
                                                   const float* __restrict__ wsp,
                                                   const float* __restrict__ bias,
                                                   float* __restrict__ out,
                                                   int K, int ldo) {
    __shared__ __align__(16) int8_t As[16384];
    __shared__ __align__(16) int8_t Bs[8192];
    const int tid = threadIdx.x;
    const int lane = tid & 63, wave = tid >> 6;
    const int wr = wave >> 1, wc = wave & 1;   // 2x2 waves over (128 rows, 64 cols)
    const int bm = blockIdx.x, bn = blockIdx.y;

    const int rA = tid >> 3;                         // [0,32)
    const int colb = (((tid & 7) ^ (rA & 7)) << 4);
    const int8_t* ap = A + (size_t)(bm * 128 + rA) * K + colb;
    const int8_t* bp = B + (size_t)(bn * 64 + rA) * K + colb;
    const size_t rstep = (size_t)32 * K;

    i32x4 acc[4][2] = {};
    const int fr = lane & 15, ks = lane >> 4;

    for (int kt = 0; kt < K; kt += 128) {
#pragma unroll
        for (int p = 0; p < 4; ++p)
            gload16(ap + kt + (size_t)p * rstep, As + p * 4096 + tid * 16);
#pragma unroll
        for (int p = 0; p < 2; ++p)
            gload16(bp + kt + (size_t)p * rstep, Bs + p * 4096 + tid * 16);
        __syncthreads();
#pragma unroll
        for (int kh = 0; kh < 2; ++kh) {
            i32x4 af[4], bf[2];
#pragma unroll
            for (int m = 0; m < 4; ++m) {
                int ra = wr * 64 + m * 16 + fr;
                af[m] = *(const i32x4*)(As + ra * 128 + (((kh * 4 + ks) ^ (ra & 7)) << 4));
            }
#pragma unroll
            for (int n = 0; n < 2; ++n) {
                int rb = wc * 32 + n * 16 + fr;      // [0,64)
                bf[n] = *(const i32x4*)(Bs + rb * 128 + (((kh * 4 + ks) ^ (rb & 7)) << 4));
            }
#pragma unroll
            for (int m = 0; m < 4; ++m)
#pragma unroll
                for (int n = 0; n < 2; ++n)
                    acc[m][n] = __builtin_amdgcn_mfma_i32_16x16x64_i8(af[m], bf[n], acc[m][n], 0, 0, 0);
        }
        __syncthreads();
    }

    const float ws = *wsp;
#pragma unroll
    for (int m = 0; m < 4; ++m) {
        int row0 = bm * 128 + wr * 64 + m * 16 + ks * 4;
#pragma unroll
        for (int n = 0; n < 2; ++n) {
            int col = bn * 64 + wc * 32 + n * 16 + fr;
            float bv = bias[col];
#pragma unroll
            for (int j = 0; j < 4; ++j) {
                int row = row0 + j;
                float v = (float)acc[m][n][j] * (xs[row] * ws * (1.0f / 127.0f)) + bv;
                out[(size_t)row * ldo + col] += v;
            }
        }
    }
}

// ---------------- fc1 fused dual-B GEMM + SwiGLU, 128x64 tile, BK=128, staged f16 out ------
__global__ __launch_bounds__(256, 4) void gemm_fc1(const int8_t* __restrict__ A,
                                                   const int8_t* __restrict__ B1,
                                                   const int8_t* __restrict__ B2,
                                                   const float* __restrict__ xs,
                                                   const float* __restrict__ wsp,
                                                   const float* __restrict__ bias,
                                                   _Float16* __restrict__ out) {
    __shared__ __align__(16) int8_t smem[32768];
    int8_t* As  = smem;
    int8_t* Bs1 = smem + 16384;
    int8_t* Bs2 = smem + 24576;
    const int tid = threadIdx.x;
    const int lane = tid & 63, wave = tid >> 6;
    const int wr = wave >> 1, wc = wave & 1;   // 2x2 waves over (128 rows, 64 cols)
    const int bm = blockIdx.x, bn = blockIdx.y;
    const int K = 1024;

    const int rA = tid >> 3;                         // [0,32)
    const int colb = (((tid & 7) ^ (rA & 7)) << 4);
    const int8_t* ap  = A  + (size_t)(bm * 128 + rA) * K + colb;
    const int8_t* b1p = B1 + (size_t)(bn * 64 + rA) * K + colb;
    const int8_t* b2p = B2 + (size_t)(bn * 64 + rA) * K + colb;
    const size_t rstep = (size_t)32 * K;

    i32x4 acc1[4][2] = {}, acc2[4][2] = {};
    const int fr = lane & 15, ks = lane >> 4;

    for (int kt = 0; kt < K; kt += 128) {
#pragma unroll
        for (int p = 0; p < 4; ++p)
            gload16(ap + kt + (size_t)p * rstep, As + p * 4096 + tid * 16);
#pragma unroll
        for (int p = 0; p < 2; ++p) {
            gload16(b1p + kt + (size_t)p * rstep, Bs1 + p * 4096 + tid * 16);
            gload16(b2p + kt + (size_t)p * rstep, Bs2 + p * 4096 + tid * 16);
        }
        __syncthreads();
#pragma unroll
        for (int kh = 0; kh < 2; ++kh) {
            i32x4 af[4], b1f[2], b2f[2];
#pragma unroll
            for (int m = 0; m < 4; ++m) {
                int ra = wr * 64 + m * 16 + fr;
                af[m] = *(const i32x4*)(As + ra * 128 + (((kh * 4 + ks) ^ (ra & 7)) << 4));
            }
#pragma unroll
            for (int n = 0; n < 2; ++n) {
                int rb = wc * 32 + n * 16 + fr;      // [0,64)
                int off = rb * 128 + (((kh * 4 + ks) ^ (rb & 7)) << 4);
                b1f[n] = *(const i32x4*)(Bs1 + off);
                b2f[n] = *(const i32x4*)(Bs2 + off);
            }
#pragma unroll
            for (int m = 0; m < 4; ++m)
#pragma unroll
                for (int n = 0; n < 2; ++n) {
                    acc1[m][n] = __builtin_amdgcn_mfma_i32_16x16x64_i8(af[m], b1f[n], acc1[m][n], 0, 0, 0);
                    acc2[m][n] = __builtin_amdgcn_mfma_i32_16x16x64_i8(af[m], b2f[n], acc2[m][n], 0, 0, 0);
                }
        }
        __syncthreads();
    }

    const float ws = *wsp;
    // stage f16 tile (128x64 = 16KB) in smem, then linear full-line stores
    _Float16* lds_h = (_Float16*)smem;
#pragma unroll
    for (int m = 0; m < 4; ++m) {
        int rl0 = wr * 64 + m * 16 + ks * 4;
#pragma unroll
        for (int n = 0; n < 2; ++n) {
            int cl = wc * 32 + n * 16 + fr;
            float ba = bias[bn * 64 + cl];
            float bg = bias[bn * 64 + cl + 4096];
#pragma unroll
            for (int j = 0; j < 4; ++j) {
                int rl = rl0 + j;
                float sc = xs[bm * 128 + rl] * ws * (1.0f / 127.0f);
                float a = (float)acc1[m][n][j] * sc + ba;
                float g = (float)acc2[m][n][j] * sc + bg;
                lds_h[rl * 64 + cl] = (_Float16)(a * g / (1.0f + expf(-g)));
            }
        }
    }
    __syncthreads();
#pragma unroll
    for (int pass = 0; pass < 4; ++pass) {
        int o = pass * 4096 + tid * 16;       // byte offset in 16KB tile
        int r = o >> 7;                        // 128B per row
        int ce = (o & 127) >> 1;               // f16 elem within row
        *(half8v*)(out + (size_t)(bm * 128 + r) * HIDF + bn * 64 + ce) =
            *(const half8v*)(smem + o);
    }
}

// ---------------- per-token head-mix softmax attention (f16 qkv in, rope fused) ----------------
__global__ __launch_bounds__(256) void attn_intra(const _Float16* __restrict__ qkv,
                                                  const float* __restrict__ ct,
                                                  const float* __restrict__ st,
                                                  float* __restrict__ o) {
    __shared__ float q_s[1024], k_s[1024], v_s[1024], p_s[256];
    int t = blockIdx.x, tid = threadIdx.x;
    int n = t & (SEQ - 1);
    int j0 = (tid & 15) * 2;
    const half4v* src = (const half4v*)(qkv + (size_t)t * 3072);
    ((float4*)q_s)[tid] = rope4(h4f(src[tid]), ct, st, n, j0);
    ((float4*)k_s)[tid] = rope4(h4f(src[256 + tid]), ct, st, n, j0);
    ((float4*)v_s)[tid] = h4f(src[512 + tid]);
    __syncthreads();
    int h = tid >> 4, g = tid & 15;
    const float4* q4 = (const float4*)q_s + h * 16;
    const float4* k4 = (const float4*)k_s + g * 16;
    float accS = 0.f;
#pragma unroll
    for (int i = 0; i < 16; ++i) {
        float4 qa = q4[i], ka = k4[i];
        accS += qa.x * ka.x + qa.y * ka.y + qa.z * ka.z + qa.w * ka.w;
    }
    accS *= 0.125f;
    float mx = accS;
#pragma unroll
    for (int o2 = 8; o2 >= 1; o2 >>= 1) mx = fmaxf(mx, __shfl_xor(mx, o2, 16));
    float e = expf(accS - mx);
    float sm = e;
#pragma unroll
    for (int o2 = 8; o2 >= 1; o2 >>= 1) sm += __shfl_xor(sm, o2, 16);
    p_s[tid] = e / sm;
    __syncthreads();
    int dq = tid & 15;
    float4 acc = {0.f, 0.f, 0.f, 0.f};
    const float4* v4 = (const float4*)v_s;
#pragma unroll
    for (int gg = 0; gg < 16; ++gg) {
        float p = p_s[h * 16 + gg];
        float4 vv = v4[gg * 16 + dq];
        acc.x += p * vv.x; acc.y += p * vv.y; acc.z += p * vv.z; acc.w += p * vv.w;
    }
    ((float4*)(o + (size_t)t * DIMC))[h * 16 + dq] = acc;
}

// ---------------- per-chunk outer product U = k^T v (f16 qkv in, rope fused on k) ----------------
__global__ __launch_bounds__(256) void u_k(const _Float16* __restrict__ qkv,
                                           const float* __restrict__ ct,
                                           const float* __restrict__ st,
                                           float* __restrict__ U) {
    __shared__ float ks_[8192], vs_[8192];
    int bid = blockIdx.x, tid = threadIdx.x;
    int c = bid >> 5, b = (bid >> 4) & 1, h = bid & 15;
    size_t tok = (size_t)(b * SEQ + c * CHUNKL);
#pragma unroll
    for (int j = 0; j < 8; ++j) {
        int idx = j * 256 + tid;
        int l = idx >> 4, c4 = idx & 15;
        int n = (int)((tok + l) & (SEQ - 1));
        const _Float16* kp = qkv + (tok + l) * 3072 + 1024 + h * 64 + c4 * 4;
        const _Float16* vp = qkv + (tok + l) * 3072 + 2048 + h * 64 + c4 * 4;
        ((float4*)ks_)[idx] = rope4(h4f(*(const half4v*)kp), ct, st, n, c4 * 2);
        ((float4*)vs_)[idx] = h4f(*(const half4v*)vp);
    }
    __syncthreads();
    int d = tid >> 2, eg = tid & 3;
    float4 acc[4] = {};
    for (int l = 0; l < CHUNKL; ++l) {
        float kd = ks_[l * 64 + d];
        const float4* vrow = (const float4*)(vs_ + l * 64) + eg * 4;
#pragma unroll
        for (int i = 0; i < 4; ++i) {
            float4 vv = vrow[i];
            acc[i].x += kd * vv.x; acc[i].y += kd * vv.y;
            acc[i].z += kd * vv.z; acc[i].w += kd * vv.w;
        }
    }
    float4* Up = (float4*)(U + (size_t)bid * 4096) + d * 16 + eg * 4;
#pragma unroll
    for (int i = 0; i < 4; ++i) Up[i] = acc[i];
}

// ---------------- diagonal-decay scan over chunks ----------------
__global__ __launch_bounds__(256) void scan_k(const float* __restrict__ U,
                                              const float* __restrict__ dec,
                                              float* __restrict__ kvprev) {
    int t = blockIdx.x * 256 + threadIdx.x;   // 131072
    int b = t >> 16;
    int h = (t >> 12) & 15;
    int d = (t >> 6) & 63;
    float val = 0.f;
#pragma unroll 1
    for (int c = 0; c < NCHUNK; ++c) {
        kvprev[(size_t)c * 131072 + t] = val;
        val = val * dec[(c * 2 + b) * 1024 + h * 64 + d] + U[(size_t)c * 131072 + t];
    }
}

// ---------------- out += q @ kv_prev (f16 qkv in, rope fused on q) ----------------
__global__ __launch_bounds__(256) void out2_k(const _Float16* __restrict__ qkv,
                                              const float* __restrict__ ct,
                                              const float* __restrict__ st,
                                              const float* __restrict__ kvprev,
                                              float* __restrict__ o) {
    __shared__ float kv_s[4096];
    __shared__ float q_s[128 * 65];
    int bid = blockIdx.x, tid = threadIdx.x;
    int c = bid >> 5, b = (bid >> 4) & 1, h = bid & 15;
    size_t tok = (size_t)(b * SEQ + c * CHUNKL);
    const float4* kvsrc = (const float4*)(kvprev + (size_t)c * 131072 + b * 65536 + h * 4096);
#pragma unroll
    for (int j = 0; j < 4; ++j) ((float4*)kv_s)[j * 256 + tid] = kvsrc[j * 256 + tid];
#pragma unroll
    for (int j = 0; j < 8; ++j) {
        int idx = j * 256 + tid;
        int l = idx >> 4, c4 = idx & 15;
        int n = (int)((tok + l) & (SEQ - 1));
        float4 qv = rope4(h4f(*(const half4v*)(qkv + (tok + l) * 3072 + h * 64 + c4 * 4)),
                          ct, st, n, c4 * 2);
        float* dq = q_s + l * 65 + c4 * 4;
        dq[0] = qv.x; dq[1] = qv.y; dq[2] = qv.z; dq[3] = qv.w;
    }
    __syncthreads();
    int l = tid >> 1, eh = tid & 1;
    float4 acc[8] = {};
    const float* qrow = q_s + l * 65;
    for (int d = 0; d < 64; ++d) {
        float qd = qrow[d];
        const float4* kvr = (const float4*)(kv_s + d * 64) + eh * 8;
#pragma unroll
        for (int i = 0; i < 8; ++i) {
            float4 kk = kvr[i];
            acc[i].x += qd * kk.x; acc[i].y += qd * kk.y;
            acc[i].z += qd * kk.z; acc[i].w += qd * kk.w;
        }
    }
    float4* op = (float4*)(o + (tok + l) * DIMC + h * 64 + eh * 32);
#pragma unroll
    for (int i = 0; i < 8; ++i) {
        float4 cur = op[i];
        cur.x += acc[i].x; cur.y += acc[i].y; cur.z += acc[i].z; cur.w += acc[i].w;
        op[i] = cur;
    }
}

// =====================================================================
extern "C" void kernel_launch(void* const* d_in, const int* in_sizes, int n_in,
                              void* d_out, int out_size, void* d_ws, size_t ws_size,
                              hipStream_t stream) {
    const float* x_in       = (const float*)d_in[0];
    const float* norm1_w    = (const float*)d_in[1];
    const float* qkv_w      = (const float*)d_in[2];
    const float* qkv_b      = (const float*)d_in[3];
    const float* gate_w     = (const float*)d_in[4];
    const float* gate_b     = (const float*)d_in[5];
    const float* proj_w     = (const float*)d_in[6];
    const float* proj_b     = (const float*)d_in[7];
    const float* attn_norm_w= (const float*)d_in[8];
    const float* norm2_w    = (const float*)d_in[9];
    const float* fc1_w      = (const float*)d_in[10];
    const float* fc1_b      = (const float*)d_in[11];
    const float* fc2_w      = (const float*)d_in[12];
    const float* fc2_b      = (const float*)d_in[13];
    float* x = (float*)d_out;

    char* wsb = (char*)d_ws;
    size_t off = 0;
    auto carve = [&](size_t bytes) { char* p = wsb + off; off = (off + bytes + 255) & ~(size_t)255; return p; };
    int8_t* q_qkv  = (int8_t*)carve(12582912);
    int8_t* q_gate = (int8_t*)carve(4194304);
    int8_t* q_proj = (int8_t*)carve(4194304);
    int8_t* q_fc1  = (int8_t*)carve(33554432);
    int8_t* q_fc2  = (int8_t*)carve(16777216);
    float*  wsc    = (float*)carve(256);
    float*  part   = (float*)carve(4096);
    float*  ropec  = (float*)carve(524288);
    float*  ropes  = (float*)carve(524288);
    int8_t* qbuf   = (int8_t*)carve(33554432);
    float*  xsbuf  = (float*)carve(32768);
    _Float16* big  = (_Float16*)carve(67108864);  // qkv f16 (50MB) / fc1-mid f16 (67MB)
    float*  attn_o = (float*)carve(33554432);
    float*  Ub     = (float*)carve(16777216);
    float*  kvprev = (float*)carve(16777216);
    float*  decayb = (float*)carve(262144);
    (void)ws_size; (void)in_sizes; (void)n_in; (void)out_size;

    hipMemcpyAsync(x, x_in, (size_t)NTOK * DIMC * sizeof(float), hipMemcpyDeviceToDevice, stream);
    ropetab_k<<<512, 256, 0, stream>>>(ropec, ropes);

    struct WSpec { const float* w; int8_t* q; int perlayer; int arr; };
    WSpec specs[5] = {
        {qkv_w,  q_qkv,  3 * DIMC * DIMC, 0},
        {gate_w, q_gate, DIMC * DIMC,     1},
        {proj_w, q_proj, DIMC * DIMC,     2},
        {fc1_w,  q_fc1,  8192 * 1024,     3},
        {fc2_w,  q_fc2,  DIMC * HIDF,     4},
    };
    for (int a = 0; a < 5; ++a) {
        prep_k<<<dim3(256, NLAYERS), 256, 0, stream>>>(specs[a].w, specs[a].q, part, specs[a].perlayer / 4);
        amean_fin<<<NLAYERS, 256, 0, stream>>>(part, wsc + specs[a].arr * 4, specs[a].perlayer);
    }

    for (int l = 0; l < NLAYERS; ++l) {
        // ---- attention ----
        rmsq_k<<<NTOK, 256, 0, stream>>>(x, norm1_w + l * DIMC, qbuf, xsbuf);
        gemm_qkvg<<<dim3(64, 32), 256, 0, stream>>>(
            qbuf, q_qkv + (size_t)l * 3145728, q_gate + (size_t)l * 1048576, xsbuf,
            wsc + 0 * 4 + l, wsc + 1 * 4 + l,
            qkv_b + l * 3072, gate_b + l * DIMC, big, decayb);
        attn_intra<<<NTOK, 256, 0, stream>>>(big, ropec, ropes, attn_o);
        u_k<<<1024, 256, 0, stream>>>(big, ropec, ropes, Ub);
        scan_k<<<512, 256, 0, stream>>>(Ub, decayb, kvprev);
        out2_k<<<1024, 256, 0, stream>>>(big, ropec, ropes, kvprev, attn_o);
        rmsq_k<<<NTOK, 256, 0, stream>>>(attn_o, attn_norm_w + l * DIMC, qbuf, xsbuf);
        gemm_n64<<<dim3(64, 16), 256, 0, stream>>>(
            qbuf, q_proj + (size_t)l * 1048576, xsbuf, wsc + 2 * 4 + l,
            proj_b + l * DIMC, x, 1024, 1024);
        // ---- mlp ----
        rmsq_k<<<NTOK, 256, 0, stream>>>(x, norm2_w + l * DIMC, qbuf, xsbuf);
        gemm_fc1<<<dim3(64, 64), 256, 0, stream>>>(
            qbuf, q_fc1 + (size_t)l * 8388608, q_fc1 + (size_t)l * 8388608 + 4194304,
            xsbuf, wsc + 3 * 4 + l, fc1_b + l * 8192, big);
        qrow_k<<<NTOK, 256, 0, stream>>>(big, qbuf, xsbuf);
        gemm_n64<<<dim3(64, 16), 256, 0, stream>>>(
            qbuf, q_fc2 + (size_t)l * 4194304, xsbuf, wsc + 4 * 4 + l,
            fc2_b + l * DIMC, x, 4096, 1024);
    }
}